// Round 4
// baseline (436.689 us; speedup 1.0000x reference)
//
#include <hip/hip_runtime.h>
#include <math.h>

#define NB 16
#define NA 16384
#define NC 81
#define TOPK 50
#define CAP 10240
#define NEGF (-__builtin_inff())
#define SUPC 0.5000000298023223876953125   // 0.5 + 2^-25 (exact in double)

// ---- workspace layout (fast path) ----
#define WS_BOXES_OFF  ((size_t)0)
#define WS_SCORE_OFF  ((size_t)(NB * NA * 4 * 4))                      // 4 MiB boxes
#define WS_IDX_OFF    (WS_SCORE_OFF + (size_t)NB * NC * CAP * 4)
#define WS_GCNT_OFF   (WS_IDX_OFF + (size_t)NB * NC * CAP * 2)
#define WS_NEEDED     (WS_GCNT_OFF + (size_t)NB * NC * 64)             // ~84 MB

// ---------------- decode + clip (bit-verified in rounds 1-3 — DO NOT TOUCH) ----------
__global__ __launch_bounds__(256) void decode_k(const float* __restrict__ loc,
                                                const float* __restrict__ anc,
                                                float* __restrict__ boxes) {
#pragma clang fp contract(off)
    int i = blockIdx.x * 256 + threadIdx.x;
    if (i >= NB * NA) return;
    int a = i & (NA - 1);
    float4 an = ((const float4*)anc)[a];
    float4 ld = ((const float4*)loc)[i];
    float cx = an.x + (ld.x * 0.1f) * an.z;
    float cy = an.y + (ld.y * 0.1f) * an.w;
    float w = an.z * (float)exp((double)(ld.z * 0.2f));
    float h = an.w * (float)exp((double)(ld.w * 0.2f));
    float x1 = cx - w * 0.5f;
    float y1 = cy - h * 0.5f;
    float x2 = x1 + w;
    float y2 = y1 + h;
    x1 = fminf(fmaxf(x1, 0.f), 1.f);
    y1 = fminf(fmaxf(y1, 0.f), 1.f);
    x2 = fminf(fmaxf(x2, 0.f), 1.f);
    y2 = fminf(fmaxf(y2, 0.f), 1.f);
    ((float4*)boxes)[i] = make_float4(x1, y1, x2, y2);
}

// ---------------- zero padded per-(b,c) counters (64B stride kills line contention) ----
__global__ void zero_k(unsigned* __restrict__ g) {
    int i = blockIdx.x * 256 + threadIdx.x;
    if (i < NB * NC * 16) g[i] = 0u;
}

// ---------------- coalesced conf scan -> per-(b,c) full >0.5 candidate lists ----------
// v2: block = (b, slab of 512 anchors), 512 threads. Each thread holds its 81 values in
// registers (no second global pass). Per-class runs ~256 entries -> ~1.05x write amp
// (round-3's 256-anchor slabs gave 40B runs shared across XCDs -> 7x amp, 455MB writes).
#define SLAB 512
#define KPT  ((SLAB * NC) / SLAB)        // 81 elements per thread

__global__ __launch_bounds__(SLAB, 2) void scanA_k(const float* __restrict__ conf,
                                                   float* __restrict__ scoreArr,
                                                   unsigned short* __restrict__ idxArr,
                                                   unsigned* __restrict__ gcnt) {
    __shared__ unsigned s_cnt[NC], s_base[NC], s_cur[NC];
    const int blkb = blockIdx.x;
    const int b = blkb >> 5, slab = blkb & 31;          // 32 slabs of 512 anchors
    const float* p = conf + ((size_t)b * NA + (size_t)slab * SLAB) * NC;
    const int t = threadIdx.x;
    if (t < NC) { s_cnt[t] = 0u; s_cur[t] = 0u; }
    __syncthreads();

    // decompose t = 81*qt + c0  (one magic div); element k lives at i = t + 512k,
    // with compile-time r_k = (512k) mod 81, s_k = (512k) div 81:
    //   c = c0 + r_k (-81 if >=81), q = qt + s_k (+1 on wrap)
    const int qt = t / NC;
    const int c0 = t - qt * NC;

    float v[KPT];
    int   cc[KPT], qq[KPT];
#pragma unroll
    for (int k = 0; k < KPT; ++k) {
        const int rk = (SLAB * k) % NC;
        const int sk = (SLAB * k) / NC;
        int c = c0 + rk, q = qt + sk;
        if (c >= NC) { c -= NC; q += 1; }
        cc[k] = c; qq[k] = q;
        v[k] = p[t + SLAB * k];
        if (v[k] > 0.5f) atomicAdd(&s_cnt[c], 1u);
    }
    __syncthreads();
    if (t < NC) s_base[t] = atomicAdd(&gcnt[((unsigned)b * NC + t) * 16u], s_cnt[t]);
    __syncthreads();
#pragma unroll
    for (int k = 0; k < KPT; ++k) {
        if (v[k] > 0.5f) {
            const int c = cc[k];
            unsigned pos = s_base[c] + atomicAdd(&s_cur[c], 1u);
            if (pos < CAP) {
                size_t o = (size_t)((unsigned)b * NC + c) * CAP + pos;
                scoreArr[o] = v[k];
                idxArr[o] = (unsigned short)(slab * SLAB + qq[k]);
            }
        }
    }
}

// ---------------- bucket-sorted lazy greedy NMS: one block per (b,c) ----------------
__global__ __launch_bounds__(256) void nmsB_k(const float* __restrict__ conf,
                                              const float* __restrict__ boxes,
                                              const float* __restrict__ scoreArr,
                                              const unsigned short* __restrict__ idxArr,
                                              const unsigned* __restrict__ gcnt,
                                              float* __restrict__ out) {
#pragma clang fp contract(off)
    const int blk = blockIdx.x;
    const int b = blk / NC, c = blk - b * NC;
    const int t = threadIdx.x;
    const int lane = t & 63, wv = t >> 6;

    __shared__ float s_sc[CAP];                 // 40960 B
    __shared__ unsigned short s_ix[CAP];        // 20480 B
    __shared__ unsigned s_off[513];             // bucket starts (desc score order)
    __shared__ unsigned s_aux[512];             // hist -> cursors
    __shared__ float s_acc[TOPK][5];            // accepted x1,y1,x2,y2,area
    __shared__ float4 s_cbox[256];              // per-round candidate boxes
    __shared__ unsigned long long s_kill[4];
    __shared__ int s_ctrl[12];
    // ctrl: 0=nacc 1=tmpcnt 2..5=chunk starts 6=chunk end 7=bptr 9=bigE0 10=bigE1 11=mode

    const float4* bb = (const float4*)boxes + (size_t)b * NA;
    float* orow = out + (size_t)blk * (TOPK * 5);
    unsigned n_real = gcnt[(unsigned)blk * 16u];

    if (t == 0) s_ctrl[0] = 0;
    __syncthreads();

    if (n_real <= CAP) {
        // =========================== fast path ===========================
        const int n = (int)n_real;
        const size_t base = (size_t)blk * CAP;

        // --- histogram over 512 score buckets (top-9 mantissa bits; exp fixed) ---
        for (int i = t; i < 512; i += 256) s_aux[i] = 0u;
        __syncthreads();
        for (int i = t; i < n; i += 256) {
            float v = scoreArr[base + i];
            unsigned bkt = 511u - ((__float_as_uint(v) >> 14) & 0x1FFu);
            atomicAdd(&s_aux[bkt], 1u);
        }
        __syncthreads();
        // --- exclusive prefix -> s_off[0..512] ---
        if (t == 0) s_off[0] = 0u;
        for (int i = t; i < 512; i += 256) s_off[i + 1] = s_aux[i];
        __syncthreads();
        for (int d = 1; d < 512; d <<= 1) {
            int i0 = 1 + t, i1 = 257 + t;
            unsigned v0 = (i0 - d >= 1) ? s_off[i0 - d] : 0u;
            unsigned v1 = (i1 - d >= 1) ? s_off[i1 - d] : 0u;
            __syncthreads();
            s_off[i0] += v0;
            s_off[i1] += v1;
            __syncthreads();
        }
        // --- cursors + scatter into bucket-ordered LDS arrays ---
        for (int i = t; i < 512; i += 256) s_aux[i] = s_off[i];
        __syncthreads();
        for (int i = t; i < n; i += 256) {
            float v = scoreArr[base + i];
            unsigned short a = idxArr[base + i];
            unsigned bkt = 511u - ((__float_as_uint(v) >> 14) & 0x1FFu);
            unsigned pos = atomicAdd(&s_aux[bkt], 1u);
            s_sc[pos] = v;
            s_ix[pos] = a;
        }
        if (t == 0) s_ctrl[7] = 0;
        __syncthreads();

        // --- rounds: 4 bucket-aligned chunks of <=64, parallel test + serial resolve ---
        while (true) {
            if (t == 0) {
                int bp = s_ctrl[7];
                int mode;
                unsigned pos = (bp < 512) ? s_off[bp] : s_off[512];
                if (bp >= 512 || pos >= (unsigned)n) {
                    mode = 2;
                } else {
                    int bpl = bp;
                    unsigned q = pos;
                    for (int w = 0; w < 4; ++w) {
                        s_ctrl[2 + w] = (int)q;
                        while (bpl < 512 && (s_off[bpl + 1] - q) <= 64u) bpl++;
                        q = (bpl < 512) ? s_off[bpl] : s_off[512];
                    }
                    s_ctrl[6] = (int)q;
                    s_ctrl[7] = bpl;
                    mode = 0;
                    if (q == pos) {            // first bucket > 64 entries (≈ never)
                        mode = 1;
                        s_ctrl[9] = (int)pos;
                        s_ctrl[10] = (int)s_off[bp + 1];
                        s_ctrl[7] = bp + 1;
                    }
                }
                s_ctrl[11] = mode;
            }
            __syncthreads();
            const int mode = s_ctrl[11];
            if (mode == 2) break;
            const int nacc0 = s_ctrl[0];

            if (mode == 0) {
                const unsigned q0 = (unsigned)s_ctrl[2 + wv];
                const unsigned q1 = (unsigned)s_ctrl[3 + wv];
                const int mw = (int)(q1 - q0);
                const bool valid = lane < mw;
                int ii = (int)q0 + lane; if (ii > CAP - 1) ii = CAP - 1;
                float v = s_sc[ii];
                int a = (int)s_ix[ii];
                float4 bxv = valid ? bb[a] : make_float4(0.f, 0.f, 0.f, 0.f);
                s_cbox[wv * 64 + lane] = bxv;
                float mar = (bxv.z - bxv.x) * (bxv.w - bxv.y);
                bool kill = !valid;
                for (int j = 0; j < nacc0; ++j) {
                    float xx1 = fmaxf(s_acc[j][0], bxv.x), yy1 = fmaxf(s_acc[j][1], bxv.y);
                    float xx2 = fminf(s_acc[j][2], bxv.z), yy2 = fminf(s_acc[j][3], bxv.w);
                    float iw = fmaxf(xx2 - xx1, 0.f), ih = fmaxf(yy2 - yy1, 0.f);
                    float inter = iw * ih;
                    float den = (s_acc[j][4] + mar) - inter;
                    if ((double)inter > (double)den * SUPC) kill = true;
                }
                unsigned long long km = __ballot(kill);
                if (lane == 0) s_kill[wv] = km;
                __syncthreads();

                if (wv == 0) {
                    int na = nacc0;
                    for (int cc = 0; cc < 4 && na < TOPK; ++cc) {
                        const unsigned e0 = (unsigned)s_ctrl[2 + cc];
                        const unsigned e1 = (unsigned)s_ctrl[3 + cc];
                        const int mc = (int)(e1 - e0);
                        if (mc <= 0) continue;
                        unsigned long long alive = ~s_kill[cc];
                        if (mc < 64) alive &= (1ull << mc) - 1ull;
                        int jj = (int)e0 + lane; if (jj > CAP - 1) jj = CAP - 1;
                        float4 mybx = s_cbox[cc * 64 + lane];
                        float mar2 = (mybx.z - mybx.x) * (mybx.w - mybx.y);
                        // delta kills: accepts made earlier this round
                        for (int j = nacc0; j < na && alive; ++j) {
                            float xx1 = fmaxf(s_acc[j][0], mybx.x), yy1 = fmaxf(s_acc[j][1], mybx.y);
                            float xx2 = fminf(s_acc[j][2], mybx.z), yy2 = fminf(s_acc[j][3], mybx.w);
                            float iw = fmaxf(xx2 - xx1, 0.f), ih = fmaxf(yy2 - yy1, 0.f);
                            float inter = iw * ih;
                            float den = (s_acc[j][4] + mar2) - inter;
                            bool sup = ((double)inter > (double)den * SUPC);
                            alive &= ~__ballot(sup);
                        }
                        unsigned long long mykey =
                            ((unsigned long long)__float_as_uint(s_sc[jj]) << 32) |
                            (unsigned)(16383 - (int)s_ix[jj]);
                        while (alive && na < TOPK) {
                            unsigned long long kk = ((alive >> lane) & 1ull) ? mykey : 0ull;
                            int src = lane;
                            for (int off = 32; off; off >>= 1) {
                                unsigned long long ok = __shfl_xor(kk, off);
                                int osrc = __shfl_xor(src, off);
                                if (ok > kk) { kk = ok; src = osrc; }
                            }
                            float4 wb = s_cbox[cc * 64 + src];
                            float wscore = s_sc[(int)e0 + src];
                            float war = (wb.z - wb.x) * (wb.w - wb.y);
                            if (lane == 0) {
                                orow[na * 5 + 0] = wscore;
                                orow[na * 5 + 1] = wb.x; orow[na * 5 + 2] = wb.y;
                                orow[na * 5 + 3] = wb.z; orow[na * 5 + 4] = wb.w;
                                s_acc[na][0] = wb.x; s_acc[na][1] = wb.y;
                                s_acc[na][2] = wb.z; s_acc[na][3] = wb.w;
                                s_acc[na][4] = war;
                            }
                            na++;
                            alive &= ~(1ull << src);
                            if (alive) {
                                float xx1 = fmaxf(wb.x, mybx.x), yy1 = fmaxf(wb.y, mybx.y);
                                float xx2 = fminf(wb.z, mybx.z), yy2 = fminf(wb.w, mybx.w);
                                float iw = fmaxf(xx2 - xx1, 0.f), ih = fmaxf(yy2 - yy1, 0.f);
                                float inter = iw * ih;
                                float den = (war + mar2) - inter;
                                bool sup = ((double)inter > (double)den * SUPC);
                                alive &= ~__ballot(sup);
                            }
                        }
                    }
                    if (lane == 0) s_ctrl[0] = na;
                }
                __syncthreads();
            } else {
                // big-bucket (>64 same-bucket candidates; ≈ never): wave-0 extraction
                const int e0 = s_ctrl[9], e1 = s_ctrl[10];
                if (wv == 0) {
                    int na = s_ctrl[0];
                    while (na < TOPK) {
                        unsigned long long bk = 0ull; int bpos = 0;
                        for (int i = e0 + lane; i < e1; i += 64) {
                            float v = s_sc[i];
                            if (v > 0.f) {
                                unsigned long long k =
                                    ((unsigned long long)__float_as_uint(v) << 32) |
                                    (unsigned)(16383 - (int)s_ix[i]);
                                if (k > bk) { bk = k; bpos = i; }
                            }
                        }
                        for (int off = 32; off; off >>= 1) {
                            unsigned long long ok = __shfl_xor(bk, off);
                            int op = __shfl_xor(bpos, off);
                            if (ok > bk) { bk = ok; bpos = op; }
                        }
                        if (bk == 0ull) break;
                        int a = (int)s_ix[bpos];
                        float wscore = s_sc[bpos];
                        if (lane == 0) s_sc[bpos] = 0.f;     // consume
                        float4 wb = bb[a];
                        float war = (wb.z - wb.x) * (wb.w - wb.y);
                        bool sup = false;
                        if (lane < na) {
                            float xx1 = fmaxf(s_acc[lane][0], wb.x), yy1 = fmaxf(s_acc[lane][1], wb.y);
                            float xx2 = fminf(s_acc[lane][2], wb.z), yy2 = fminf(s_acc[lane][3], wb.w);
                            float iw = fmaxf(xx2 - xx1, 0.f), ih = fmaxf(yy2 - yy1, 0.f);
                            float inter = iw * ih;
                            float den = (s_acc[lane][4] + war) - inter;
                            sup = ((double)inter > (double)den * SUPC);
                        }
                        if (__ballot(sup) == 0ull) {
                            if (lane == 0) {
                                orow[na * 5 + 0] = wscore;
                                orow[na * 5 + 1] = wb.x; orow[na * 5 + 2] = wb.y;
                                orow[na * 5 + 3] = wb.z; orow[na * 5 + 4] = wb.w;
                                s_acc[na][0] = wb.x; s_acc[na][1] = wb.y;
                                s_acc[na][2] = wb.z; s_acc[na][3] = wb.w;
                                s_acc[na][4] = war;
                            }
                            na++;
                        }
                    }
                    if (lane == 0) s_ctrl[0] = na;
                }
                __syncthreads();
            }
            if (s_ctrl[0] >= TOPK) break;
        }
    } else {
        // ====================== exact windowed path (n > CAP; ≈ never) ======================
        const float* cp = conf + ((size_t)b * NA) * NC + c;
        float hi = 1.0f, delta = 0.02f;
        while (true) {
            if (s_ctrl[0] >= TOPK || hi <= 0.5f) break;
            float lo = fmaxf(hi - delta, 0.5f);
            if (t == 0) s_ctrl[1] = 0;
            __syncthreads();
            for (int a = t; a < NA; a += 256) {
                float v = cp[(size_t)a * NC];
                if (v > lo && v <= hi) {
                    int pos = atomicAdd(&s_ctrl[1], 1);
                    if (pos < CAP) { s_sc[pos] = v; s_ix[pos] = (unsigned short)a; }
                }
            }
            __syncthreads();
            int m = s_ctrl[1];
            if (m > CAP) { delta *= 0.5f; __syncthreads(); continue; }
            if (wv == 0) {
                int na = s_ctrl[0];
                while (na < TOPK) {
                    unsigned long long bk = 0ull; int bpos = 0;
                    for (int i = lane; i < m; i += 64) {
                        float v = s_sc[i];
                        if (v > 0.f) {
                            unsigned long long k =
                                ((unsigned long long)__float_as_uint(v) << 32) |
                                (unsigned)(16383 - (int)s_ix[i]);
                            if (k > bk) { bk = k; bpos = i; }
                        }
                    }
                    for (int off = 32; off; off >>= 1) {
                        unsigned long long ok = __shfl_xor(bk, off);
                        int op = __shfl_xor(bpos, off);
                        if (ok > bk) { bk = ok; bpos = op; }
                    }
                    if (bk == 0ull) break;
                    int a = (int)s_ix[bpos];
                    float wscore = s_sc[bpos];
                    if (lane == 0) s_sc[bpos] = 0.f;
                    float4 wb = bb[a];
                    float war = (wb.z - wb.x) * (wb.w - wb.y);
                    bool sup = false;
                    if (lane < na) {
                        float xx1 = fmaxf(s_acc[lane][0], wb.x), yy1 = fmaxf(s_acc[lane][1], wb.y);
                        float xx2 = fminf(s_acc[lane][2], wb.z), yy2 = fminf(s_acc[lane][3], wb.w);
                        float iw = fmaxf(xx2 - xx1, 0.f), ih = fmaxf(yy2 - yy1, 0.f);
                        float inter = iw * ih;
                        float den = (s_acc[lane][4] + war) - inter;
                        sup = ((double)inter > (double)den * SUPC);
                    }
                    if (__ballot(sup) == 0ull) {
                        if (lane == 0) {
                            orow[na * 5 + 0] = wscore;
                            orow[na * 5 + 1] = wb.x; orow[na * 5 + 2] = wb.y;
                            orow[na * 5 + 3] = wb.z; orow[na * 5 + 4] = wb.w;
                            s_acc[na][0] = wb.x; s_acc[na][1] = wb.y;
                            s_acc[na][2] = wb.z; s_acc[na][3] = wb.w;
                            s_acc[na][4] = war;
                        }
                        na++;
                    }
                }
                if (lane == 0) s_ctrl[0] = na;
            }
            __syncthreads();
            hi = lo;
        }
    }

    __syncthreads();
    const int naF = s_ctrl[0];
    for (int z = naF * 5 + t; z < TOPK * 5; z += 256) orow[z] = 0.f;
}

// ============== round-1 fallback (only if ws too small for fast path) ==============
#define OTHREADS 1024
#define OCAP 10240
#define OJMAX 10

__global__ __launch_bounds__(OTHREADS) void nms_old_k(const float* __restrict__ conf,
                                                      const float* __restrict__ boxes,
                                                      float* __restrict__ out) {
#pragma clang fp contract(off)
    const int blk = blockIdx.x;
    const int b = blk / NC, c = blk - b * NC;
    const int t = threadIdx.x;
    const int lane = t & 63, wid = t >> 6;
    __shared__ float s_val[OCAP];
    __shared__ unsigned short s_idx[OCAP];
    __shared__ float s_ps[2][16];
    __shared__ int s_pa[2][16];
    __shared__ int s_n;
    if (t == 0) s_n = 0;
    __syncthreads();
    const float* cp = conf + ((size_t)b * NA) * NC + c;
    float v[NA / OTHREADS];
#pragma unroll
    for (int r = 0; r < NA / OTHREADS; ++r)
        v[r] = cp[(size_t)(r * OTHREADS + t) * NC];
#pragma unroll
    for (int r = 0; r < NA / OTHREADS; ++r) {
        int a = r * OTHREADS + t;
        bool alive = v[r] > 0.5f;
        unsigned long long m = __ballot(alive);
        int cnt = __popcll(m);
        int base = 0;
        if (lane == 0 && cnt) base = atomicAdd(&s_n, cnt);
        base = __shfl(base, 0);
        if (alive) {
            int p = base + __popcll(m & ((1ull << lane) - 1));
            if (p < OCAP) { s_val[p] = v[r]; s_idx[p] = (unsigned short)a; }
        }
    }
    __syncthreads();
    int n = s_n; if (n > OCAP) n = OCAP;
    const int jn = (n + OTHREADS - 1) / OTHREADS;
    const float4* bb = (const float4*)boxes + (size_t)b * NA;
    float sc[OJMAX]; float4 bx[OJMAX]; int ia[OJMAX];
#pragma unroll
    for (int j = 0; j < OJMAX; ++j) {
        sc[j] = NEGF; ia[j] = 0x7fffffff; bx[j] = make_float4(0.f, 0.f, 0.f, 0.f);
        int p = j * OTHREADS + t;
        if (p < n) { sc[j] = s_val[p]; ia[j] = (int)s_idx[p]; bx[j] = bb[ia[j]]; }
    }
    float* orow = out + (size_t)blk * (TOPK * 5);
    int k = 0;
    for (; k < TOPK; ++k) {
        float ms = NEGF; int ma = 0x7fffffff;
#pragma unroll
        for (int j = 0; j < OJMAX; ++j) {
            if (j < jn) {
                bool better = (sc[j] > ms) || (sc[j] == ms && ia[j] < ma);
                ms = better ? sc[j] : ms;
                ma = better ? ia[j] : ma;
            }
        }
#pragma unroll
        for (int off = 32; off; off >>= 1) {
            float os = __shfl_xor(ms, off);
            int oa = __shfl_xor(ma, off);
            if (os > ms || (os == ms && oa < ma)) { ms = os; ma = oa; }
        }
        int pb = k & 1;
        if (lane == 0) { s_ps[pb][wid] = ms; s_pa[pb][wid] = ma; }
        __syncthreads();
        float wsv = NEGF; int wa = 0x7fffffff;
#pragma unroll
        for (int w = 0; w < 16; ++w) {
            float os = s_ps[pb][w]; int oa = s_pa[pb][w];
            if (os > wsv || (os == wsv && oa < wa)) { wsv = os; wa = oa; }
        }
        if (!(wsv > NEGF)) break;
        float4 wb = bb[wa];
        float warea = (wb.z - wb.x) * (wb.w - wb.y);
        if (t == 0) {
            orow[k * 5 + 0] = wsv;
            orow[k * 5 + 1] = wb.x; orow[k * 5 + 2] = wb.y;
            orow[k * 5 + 3] = wb.z; orow[k * 5 + 4] = wb.w;
        }
#pragma unroll
        for (int j = 0; j < OJMAX; ++j) {
            if (j < jn) {
                float xx1 = fmaxf(wb.x, bx[j].x);
                float yy1 = fmaxf(wb.y, bx[j].y);
                float xx2 = fminf(wb.z, bx[j].z);
                float yy2 = fminf(wb.w, bx[j].w);
                float iw = fmaxf(xx2 - xx1, 0.f);
                float ih = fmaxf(yy2 - yy1, 0.f);
                float inter = iw * ih;
                float aj = (bx[j].z - bx[j].x) * (bx[j].w - bx[j].y);
                float denom = (warea + aj) - inter;
                bool supp = ((double)inter > (double)denom * SUPC) || (ia[j] == wa);
                if (supp) sc[j] = NEGF;
            }
        }
    }
    for (int z = k * 5 + t; z < TOPK * 5; z += OTHREADS) orow[z] = 0.f;
}

extern "C" void kernel_launch(void* const* d_in, const int* in_sizes, int n_in,
                              void* d_out, int out_size, void* d_ws, size_t ws_size,
                              hipStream_t stream) {
    const float* conf = (const float*)d_in[0];   // [B,A,C] f32
    const float* loc  = (const float*)d_in[1];   // [B,A,4] f32
    const float* anc  = (const float*)d_in[2];   // [A,4]   f32
    float* boxes = (float*)((char*)d_ws + WS_BOXES_OFF);

    decode_k<<<(NB * NA + 255) / 256, 256, 0, stream>>>(loc, anc, boxes);

    if (ws_size >= WS_NEEDED) {
        float* scoreArr = (float*)((char*)d_ws + WS_SCORE_OFF);
        unsigned short* idxArr = (unsigned short*)((char*)d_ws + WS_IDX_OFF);
        unsigned* gcnt = (unsigned*)((char*)d_ws + WS_GCNT_OFF);
        zero_k<<<(NB * NC * 16 + 255) / 256, 256, 0, stream>>>(gcnt);
        scanA_k<<<NB * 32, SLAB, 0, stream>>>(conf, scoreArr, idxArr, gcnt);
        nmsB_k<<<NB * NC, 256, 0, stream>>>(conf, boxes, scoreArr, idxArr, gcnt,
                                            (float*)d_out);
    } else {
        nms_old_k<<<NB * NC, OTHREADS, 0, stream>>>(conf, boxes, (float*)d_out);
    }
}

// Round 5
// 241.941 us; speedup vs baseline: 1.8049x; 1.8049x over previous
//
#include <hip/hip_runtime.h>
#include <math.h>

#define NB 16
#define NA 16384
#define NC 81
#define TOPK 50
#define CAP 10240
#define NEGF (-__builtin_inff())
#define SUPC 0.5000000298023223876953125   // 0.5 + 2^-25 (exact in double)

typedef unsigned long long ull;

// ws layout: boxes [NB*NA*4 f32] @0 (4 MiB), confT [nb*NC*NA f32] @4 MiB
#define WS_CONFT_OFF  ((size_t)4194304)
#define WS_FULL  (WS_CONFT_OFF + (size_t)NB * NC * NA * 4)   // 89,128,960
#define WS_HALF  (WS_CONFT_OFF + (size_t)8  * NC * NA * 4)   // 46,661,632

// ---------------- decode + clip (bit-verified rounds 1-4 — DO NOT TOUCH) ----------
__global__ __launch_bounds__(256) void decode_k(const float* __restrict__ loc,
                                                const float* __restrict__ anc,
                                                float* __restrict__ boxes) {
#pragma clang fp contract(off)
    int i = blockIdx.x * 256 + threadIdx.x;
    if (i >= NB * NA) return;
    int a = i & (NA - 1);
    float4 an = ((const float4*)anc)[a];
    float4 ld = ((const float4*)loc)[i];
    float cx = an.x + (ld.x * 0.1f) * an.z;
    float cy = an.y + (ld.y * 0.1f) * an.w;
    float w = an.z * (float)exp((double)(ld.z * 0.2f));
    float h = an.w * (float)exp((double)(ld.w * 0.2f));
    float x1 = cx - w * 0.5f;
    float y1 = cy - h * 0.5f;
    float x2 = x1 + w;
    float y2 = y1 + h;
    x1 = fminf(fmaxf(x1, 0.f), 1.f);
    y1 = fminf(fmaxf(y1, 0.f), 1.f);
    x2 = fminf(fmaxf(x2, 0.f), 1.f);
    y2 = fminf(fmaxf(y2, 0.f), 1.f);
    ((float4*)boxes)[i] = make_float4(x1, y1, x2, y2);
}

// ---------------- tiled transpose conf [B,A,C] -> confT [nb,C,A] ----------------
// Pure coalesced r/w, no atomics — replaces the latency-bound scanA scatter.
__global__ __launch_bounds__(256) void transpose_k(const float* __restrict__ conf,
                                                   float* __restrict__ confT, int b0) {
    __shared__ float tile[32][33];
    const int a0 = blockIdx.x * 32;
    const int c0 = blockIdx.y * 32;
    const int bl = blockIdx.z;                 // local batch within this confT
    const int b = b0 + bl;
    const int tx = threadIdx.x & 31, ty = threadIdx.x >> 5;
    const float* src = conf + ((size_t)b * NA + a0) * NC + c0;
#pragma unroll
    for (int j = 0; j < 4; ++j) {
        int ar = ty + j * 8;
        if (c0 + tx < NC) tile[ar][tx] = src[(size_t)ar * NC + tx];
    }
    __syncthreads();
    float* dst = confT + ((size_t)bl * NC + c0) * NA + a0;
#pragma unroll
    for (int j = 0; j < 4; ++j) {
        int cr = ty + j * 8;
        if (c0 + cr < NC) dst[(size_t)cr * NA + tx] = tile[tx][cr];
    }
}

// ---------------- bucket-sorted lazy greedy NMS v2: contiguous row source ----------
// s_ix only in LDS (~30 KB total -> 5 blocks/CU); scores gathered from L1/L2-hot row.
__global__ __launch_bounds__(256, 5) void nmsB2_k(const float* __restrict__ confT,
                                                  const float* __restrict__ boxes,
                                                  float* __restrict__ out, int b0) {
#pragma clang fp contract(off)
    const int blk = blockIdx.x;
    const int bl = blk / NC, c = blk - bl * NC;
    const int b = b0 + bl;
    const int t = threadIdx.x;
    const int lane = t & 63, wv = t >> 6;

    __shared__ unsigned short s_ix[CAP];        // 20480 B
    __shared__ unsigned s_off[513];             // bucket starts (desc score order)
    __shared__ unsigned s_aux[512];             // hist -> cursors
    __shared__ float s_acc[TOPK][5];            // accepted x1,y1,x2,y2,area
    __shared__ float4 s_cbox[256];              // per-round candidate boxes
    __shared__ unsigned long long s_kill[4];
    __shared__ int s_ctrl[12];
    // ctrl: 0=nacc 1=tmpcnt 2..5=chunk starts 6=chunk end 7=bptr 9=bigE0 10=bigE1 11=mode

    const float* row = confT + ((size_t)bl * NC + c) * NA;
    const float4* row4 = (const float4*)row;
    const float4* bb = (const float4*)boxes + (size_t)b * NA;
    float* orow = out + ((size_t)b * NC + c) * (TOPK * 5);

    // --- histogram over 512 score buckets (top-9 mantissa bits; exp fixed for (.5,1)) ---
    for (int i = t; i < 512; i += 256) s_aux[i] = 0u;
    if (t == 0) s_ctrl[0] = 0;
    __syncthreads();
#pragma unroll 4
    for (int r = 0; r < 16; ++r) {
        float4 v4 = row4[t + 256 * r];
        if (v4.x > 0.5f) atomicAdd(&s_aux[511u - ((__float_as_uint(v4.x) >> 14) & 0x1FFu)], 1u);
        if (v4.y > 0.5f) atomicAdd(&s_aux[511u - ((__float_as_uint(v4.y) >> 14) & 0x1FFu)], 1u);
        if (v4.z > 0.5f) atomicAdd(&s_aux[511u - ((__float_as_uint(v4.z) >> 14) & 0x1FFu)], 1u);
        if (v4.w > 0.5f) atomicAdd(&s_aux[511u - ((__float_as_uint(v4.w) >> 14) & 0x1FFu)], 1u);
    }
    __syncthreads();
    // --- exclusive prefix -> s_off[0..512] (verified r3/r4 pattern) ---
    if (t == 0) s_off[0] = 0u;
    for (int i = t; i < 512; i += 256) s_off[i + 1] = s_aux[i];
    __syncthreads();
    for (int d = 1; d < 512; d <<= 1) {
        int i0 = 1 + t, i1 = 257 + t;
        unsigned v0 = (i0 - d >= 1) ? s_off[i0 - d] : 0u;
        unsigned v1 = (i1 - d >= 1) ? s_off[i1 - d] : 0u;
        __syncthreads();
        s_off[i0] += v0;
        s_off[i1] += v1;
        __syncthreads();
    }
    const int n = (int)s_off[512];

    if (n <= CAP) {
        // =========================== fast path ===========================
        // --- cursors + scatter anchor idx into bucket-ordered s_ix ---
        for (int i = t; i < 512; i += 256) s_aux[i] = s_off[i];
        __syncthreads();
#pragma unroll 4
        for (int r = 0; r < 16; ++r) {
            float4 v4 = row4[t + 256 * r];
            int a0i = 4 * (t + 256 * r);
            if (v4.x > 0.5f) s_ix[atomicAdd(&s_aux[511u - ((__float_as_uint(v4.x) >> 14) & 0x1FFu)], 1u)] = (unsigned short)(a0i + 0);
            if (v4.y > 0.5f) s_ix[atomicAdd(&s_aux[511u - ((__float_as_uint(v4.y) >> 14) & 0x1FFu)], 1u)] = (unsigned short)(a0i + 1);
            if (v4.z > 0.5f) s_ix[atomicAdd(&s_aux[511u - ((__float_as_uint(v4.z) >> 14) & 0x1FFu)], 1u)] = (unsigned short)(a0i + 2);
            if (v4.w > 0.5f) s_ix[atomicAdd(&s_aux[511u - ((__float_as_uint(v4.w) >> 14) & 0x1FFu)], 1u)] = (unsigned short)(a0i + 3);
        }
        if (t == 0) s_ctrl[7] = 0;
        __syncthreads();

        // --- rounds: 4 bucket-aligned chunks of <=64, parallel test + serial resolve ---
        while (true) {
            if (t == 0) {
                int bp = s_ctrl[7];
                int mode;
                unsigned pos = (bp < 512) ? s_off[bp] : s_off[512];
                if (bp >= 512 || pos >= (unsigned)n) {
                    mode = 2;
                } else {
                    int bpl = bp;
                    unsigned q = pos;
                    for (int w = 0; w < 4; ++w) {
                        s_ctrl[2 + w] = (int)q;
                        while (bpl < 512 && (s_off[bpl + 1] - q) <= 64u) bpl++;
                        q = (bpl < 512) ? s_off[bpl] : s_off[512];
                    }
                    s_ctrl[6] = (int)q;
                    s_ctrl[7] = bpl;
                    mode = 0;
                    if (q == pos) {            // first bucket > 64 entries (≈ never)
                        mode = 1;
                        s_ctrl[9] = (int)pos;
                        s_ctrl[10] = (int)s_off[bp + 1];
                        s_ctrl[7] = bp + 1;
                    }
                }
                s_ctrl[11] = mode;
            }
            __syncthreads();
            const int mode = s_ctrl[11];
            if (mode == 2) break;
            const int nacc0 = s_ctrl[0];

            if (mode == 0) {
                const unsigned q0 = (unsigned)s_ctrl[2 + wv];
                const unsigned q1 = (unsigned)s_ctrl[3 + wv];
                const int mw = (int)(q1 - q0);
                const bool valid = lane < mw;
                int ii = (int)q0 + lane; if (ii > CAP - 1) ii = CAP - 1;
                int a = valid ? (int)s_ix[ii] : 0;
                float4 bxv = bb[a];
                if (!valid) bxv = make_float4(0.f, 0.f, 0.f, 0.f);
                s_cbox[wv * 64 + lane] = bxv;
                float mar = (bxv.z - bxv.x) * (bxv.w - bxv.y);
                bool kill = !valid;
                for (int j = 0; j < nacc0; ++j) {
                    float xx1 = fmaxf(s_acc[j][0], bxv.x), yy1 = fmaxf(s_acc[j][1], bxv.y);
                    float xx2 = fminf(s_acc[j][2], bxv.z), yy2 = fminf(s_acc[j][3], bxv.w);
                    float iw = fmaxf(xx2 - xx1, 0.f), ih = fmaxf(yy2 - yy1, 0.f);
                    float inter = iw * ih;
                    float den = (s_acc[j][4] + mar) - inter;
                    if ((double)inter > (double)den * SUPC) kill = true;
                }
                unsigned long long km = __ballot(kill);
                if (lane == 0) s_kill[wv] = km;
                __syncthreads();

                if (wv == 0) {
                    int na = nacc0;
                    for (int cc = 0; cc < 4 && na < TOPK; ++cc) {
                        const unsigned e0 = (unsigned)s_ctrl[2 + cc];
                        const unsigned e1 = (unsigned)s_ctrl[3 + cc];
                        const int mc = (int)(e1 - e0);
                        if (mc <= 0) continue;
                        unsigned long long alive = ~s_kill[cc];
                        if (mc < 64) alive &= (1ull << mc) - 1ull;
                        int jj = (int)e0 + lane; if (jj > CAP - 1) jj = CAP - 1;
                        int aj = (lane < mc) ? (int)s_ix[jj] : 0;
                        float myscore = row[aj];                       // L1/L2-hot gather
                        float4 mybx = s_cbox[cc * 64 + lane];
                        float mar2 = (mybx.z - mybx.x) * (mybx.w - mybx.y);
                        // delta kills: accepts made earlier this round
                        for (int j = nacc0; j < na && alive; ++j) {
                            float xx1 = fmaxf(s_acc[j][0], mybx.x), yy1 = fmaxf(s_acc[j][1], mybx.y);
                            float xx2 = fminf(s_acc[j][2], mybx.z), yy2 = fminf(s_acc[j][3], mybx.w);
                            float iw = fmaxf(xx2 - xx1, 0.f), ih = fmaxf(yy2 - yy1, 0.f);
                            float inter = iw * ih;
                            float den = (s_acc[j][4] + mar2) - inter;
                            bool sup = ((double)inter > (double)den * SUPC);
                            alive &= ~__ballot(sup);
                        }
                        unsigned long long mykey =
                            ((unsigned long long)__float_as_uint(myscore) << 32) |
                            (unsigned)(16383 - aj);
                        while (alive && na < TOPK) {
                            unsigned long long kk = ((alive >> lane) & 1ull) ? mykey : 0ull;
                            int src = lane;
                            for (int off = 32; off; off >>= 1) {
                                unsigned long long ok = __shfl_xor(kk, off);
                                int osrc = __shfl_xor(src, off);
                                if (ok > kk) { kk = ok; src = osrc; }
                            }
                            float4 wb = s_cbox[cc * 64 + src];
                            float wscore = __shfl(myscore, src);
                            float war = (wb.z - wb.x) * (wb.w - wb.y);
                            if (lane == 0) {
                                orow[na * 5 + 0] = wscore;
                                orow[na * 5 + 1] = wb.x; orow[na * 5 + 2] = wb.y;
                                orow[na * 5 + 3] = wb.z; orow[na * 5 + 4] = wb.w;
                                s_acc[na][0] = wb.x; s_acc[na][1] = wb.y;
                                s_acc[na][2] = wb.z; s_acc[na][3] = wb.w;
                                s_acc[na][4] = war;
                            }
                            na++;
                            alive &= ~(1ull << src);
                            if (alive) {
                                float xx1 = fmaxf(wb.x, mybx.x), yy1 = fmaxf(wb.y, mybx.y);
                                float xx2 = fminf(wb.z, mybx.z), yy2 = fminf(wb.w, mybx.w);
                                float iw = fmaxf(xx2 - xx1, 0.f), ih = fmaxf(yy2 - yy1, 0.f);
                                float inter = iw * ih;
                                float den = (war + mar2) - inter;
                                bool sup = ((double)inter > (double)den * SUPC);
                                alive &= ~__ballot(sup);
                            }
                        }
                    }
                    if (lane == 0) s_ctrl[0] = na;
                }
                __syncthreads();
            } else {
                // big-bucket (>64 same-bucket candidates; ≈ never): wave-0 extraction
                const int e0 = s_ctrl[9], e1 = s_ctrl[10];
                if (wv == 0) {
                    int na = s_ctrl[0];
                    while (na < TOPK) {
                        unsigned long long bk = 0ull; int bpos = 0;
                        for (int i = e0 + lane; i < e1; i += 64) {
                            int av = (int)s_ix[i];
                            if (av != 0xFFFF) {
                                float v = row[av];
                                unsigned long long k =
                                    ((unsigned long long)__float_as_uint(v) << 32) |
                                    (unsigned)(16383 - av);
                                if (k > bk) { bk = k; bpos = i; }
                            }
                        }
                        for (int off = 32; off; off >>= 1) {
                            unsigned long long ok = __shfl_xor(bk, off);
                            int op = __shfl_xor(bpos, off);
                            if (ok > bk) { bk = ok; bpos = op; }
                        }
                        if (bk == 0ull) break;
                        int a = (int)s_ix[bpos];
                        float wscore = __uint_as_float((unsigned)(bk >> 32));
                        if (lane == 0) s_ix[bpos] = 0xFFFFu;     // consume
                        float4 wb = bb[a];
                        float war = (wb.z - wb.x) * (wb.w - wb.y);
                        bool sup = false;
                        if (lane < na) {
                            float xx1 = fmaxf(s_acc[lane][0], wb.x), yy1 = fmaxf(s_acc[lane][1], wb.y);
                            float xx2 = fminf(s_acc[lane][2], wb.z), yy2 = fminf(s_acc[lane][3], wb.w);
                            float iw = fmaxf(xx2 - xx1, 0.f), ih = fmaxf(yy2 - yy1, 0.f);
                            float inter = iw * ih;
                            float den = (s_acc[lane][4] + war) - inter;
                            sup = ((double)inter > (double)den * SUPC);
                        }
                        if (__ballot(sup) == 0ull) {
                            if (lane == 0) {
                                orow[na * 5 + 0] = wscore;
                                orow[na * 5 + 1] = wb.x; orow[na * 5 + 2] = wb.y;
                                orow[na * 5 + 3] = wb.z; orow[na * 5 + 4] = wb.w;
                                s_acc[na][0] = wb.x; s_acc[na][1] = wb.y;
                                s_acc[na][2] = wb.z; s_acc[na][3] = wb.w;
                                s_acc[na][4] = war;
                            }
                            na++;
                        }
                    }
                    if (lane == 0) s_ctrl[0] = na;
                }
                __syncthreads();
            }
            if (s_ctrl[0] >= TOPK) break;
        }
    } else {
        // ========== exact windowed path (n > CAP; ≈ never, row is contiguous) ==========
        float hi = 1.0f, delta = 0.02f;
        while (true) {
            if (s_ctrl[0] >= TOPK || hi <= 0.5f) break;
            float lo = fmaxf(hi - delta, 0.5f);
            if (t == 0) s_ctrl[1] = 0;
            __syncthreads();
            for (int r = 0; r < 16; ++r) {
                float4 v4 = row4[t + 256 * r];
                int a0i = 4 * (t + 256 * r);
                if (v4.x > lo && v4.x <= hi) { int p = atomicAdd(&s_ctrl[1], 1); if (p < CAP) s_ix[p] = (unsigned short)(a0i + 0); }
                if (v4.y > lo && v4.y <= hi) { int p = atomicAdd(&s_ctrl[1], 1); if (p < CAP) s_ix[p] = (unsigned short)(a0i + 1); }
                if (v4.z > lo && v4.z <= hi) { int p = atomicAdd(&s_ctrl[1], 1); if (p < CAP) s_ix[p] = (unsigned short)(a0i + 2); }
                if (v4.w > lo && v4.w <= hi) { int p = atomicAdd(&s_ctrl[1], 1); if (p < CAP) s_ix[p] = (unsigned short)(a0i + 3); }
            }
            __syncthreads();
            int m = s_ctrl[1];
            if (m > CAP) { delta *= 0.5f; continue; }
            if (wv == 0) {
                int na = s_ctrl[0];
                while (na < TOPK) {
                    unsigned long long bk = 0ull; int bpos = 0;
                    for (int i = lane; i < m; i += 64) {
                        int av = (int)s_ix[i];
                        if (av != 0xFFFF) {
                            float v = row[av];
                            unsigned long long k =
                                ((unsigned long long)__float_as_uint(v) << 32) |
                                (unsigned)(16383 - av);
                            if (k > bk) { bk = k; bpos = i; }
                        }
                    }
                    for (int off = 32; off; off >>= 1) {
                        unsigned long long ok = __shfl_xor(bk, off);
                        int op = __shfl_xor(bpos, off);
                        if (ok > bk) { bk = ok; bpos = op; }
                    }
                    if (bk == 0ull) break;
                    int a = (int)s_ix[bpos];
                    float wscore = __uint_as_float((unsigned)(bk >> 32));
                    if (lane == 0) s_ix[bpos] = 0xFFFFu;
                    float4 wb = bb[a];
                    float war = (wb.z - wb.x) * (wb.w - wb.y);
                    bool sup = false;
                    if (lane < na) {
                        float xx1 = fmaxf(s_acc[lane][0], wb.x), yy1 = fmaxf(s_acc[lane][1], wb.y);
                        float xx2 = fminf(s_acc[lane][2], wb.z), yy2 = fminf(s_acc[lane][3], wb.w);
                        float iw = fmaxf(xx2 - xx1, 0.f), ih = fmaxf(yy2 - yy1, 0.f);
                        float inter = iw * ih;
                        float den = (s_acc[lane][4] + war) - inter;
                        sup = ((double)inter > (double)den * SUPC);
                    }
                    if (__ballot(sup) == 0ull) {
                        if (lane == 0) {
                            orow[na * 5 + 0] = wscore;
                            orow[na * 5 + 1] = wb.x; orow[na * 5 + 2] = wb.y;
                            orow[na * 5 + 3] = wb.z; orow[na * 5 + 4] = wb.w;
                            s_acc[na][0] = wb.x; s_acc[na][1] = wb.y;
                            s_acc[na][2] = wb.z; s_acc[na][3] = wb.w;
                            s_acc[na][4] = war;
                        }
                        na++;
                    }
                }
                if (lane == 0) s_ctrl[0] = na;
            }
            __syncthreads();
            hi = lo;
        }
    }

    __syncthreads();
    const int naF = s_ctrl[0];
    for (int z = naF * 5 + t; z < TOPK * 5; z += 256) orow[z] = 0.f;
}

// ============== round-1 fallback (only if ws too small for fast paths) ==============
#define OTHREADS 1024
#define OCAP 10240
#define OJMAX 10

__global__ __launch_bounds__(OTHREADS) void nms_old_k(const float* __restrict__ conf,
                                                      const float* __restrict__ boxes,
                                                      float* __restrict__ out) {
#pragma clang fp contract(off)
    const int blk = blockIdx.x;
    const int b = blk / NC, c = blk - b * NC;
    const int t = threadIdx.x;
    const int lane = t & 63, wid = t >> 6;
    __shared__ float s_val[OCAP];
    __shared__ unsigned short s_idx[OCAP];
    __shared__ float s_ps[2][16];
    __shared__ int s_pa[2][16];
    __shared__ int s_n;
    if (t == 0) s_n = 0;
    __syncthreads();
    const float* cp = conf + ((size_t)b * NA) * NC + c;
    float v[NA / OTHREADS];
#pragma unroll
    for (int r = 0; r < NA / OTHREADS; ++r)
        v[r] = cp[(size_t)(r * OTHREADS + t) * NC];
#pragma unroll
    for (int r = 0; r < NA / OTHREADS; ++r) {
        int a = r * OTHREADS + t;
        bool alive = v[r] > 0.5f;
        unsigned long long m = __ballot(alive);
        int cnt = __popcll(m);
        int base = 0;
        if (lane == 0 && cnt) base = atomicAdd(&s_n, cnt);
        base = __shfl(base, 0);
        if (alive) {
            int p = base + __popcll(m & ((1ull << lane) - 1));
            if (p < OCAP) { s_val[p] = v[r]; s_idx[p] = (unsigned short)a; }
        }
    }
    __syncthreads();
    int n = s_n; if (n > OCAP) n = OCAP;
    const int jn = (n + OTHREADS - 1) / OTHREADS;
    const float4* bb = (const float4*)boxes + (size_t)b * NA;
    float sc[OJMAX]; float4 bx[OJMAX]; int ia[OJMAX];
#pragma unroll
    for (int j = 0; j < OJMAX; ++j) {
        sc[j] = NEGF; ia[j] = 0x7fffffff; bx[j] = make_float4(0.f, 0.f, 0.f, 0.f);
        int p = j * OTHREADS + t;
        if (p < n) { sc[j] = s_val[p]; ia[j] = (int)s_idx[p]; bx[j] = bb[ia[j]]; }
    }
    float* orow = out + (size_t)blk * (TOPK * 5);
    int k = 0;
    for (; k < TOPK; ++k) {
        float ms = NEGF; int ma = 0x7fffffff;
#pragma unroll
        for (int j = 0; j < OJMAX; ++j) {
            if (j < jn) {
                bool better = (sc[j] > ms) || (sc[j] == ms && ia[j] < ma);
                ms = better ? sc[j] : ms;
                ma = better ? ia[j] : ma;
            }
        }
#pragma unroll
        for (int off = 32; off; off >>= 1) {
            float os = __shfl_xor(ms, off);
            int oa = __shfl_xor(ma, off);
            if (os > ms || (os == ms && oa < ma)) { ms = os; ma = oa; }
        }
        int pb = k & 1;
        if (lane == 0) { s_ps[pb][wid] = ms; s_pa[pb][wid] = ma; }
        __syncthreads();
        float wsv = NEGF; int wa = 0x7fffffff;
#pragma unroll
        for (int w = 0; w < 16; ++w) {
            float os = s_ps[pb][w]; int oa = s_pa[pb][w];
            if (os > wsv || (os == wsv && oa < wa)) { wsv = os; wa = oa; }
        }
        if (!(wsv > NEGF)) break;
        float4 wb = bb[wa];
        float warea = (wb.z - wb.x) * (wb.w - wb.y);
        if (t == 0) {
            orow[k * 5 + 0] = wsv;
            orow[k * 5 + 1] = wb.x; orow[k * 5 + 2] = wb.y;
            orow[k * 5 + 3] = wb.z; orow[k * 5 + 4] = wb.w;
        }
#pragma unroll
        for (int j = 0; j < OJMAX; ++j) {
            if (j < jn) {
                float xx1 = fmaxf(wb.x, bx[j].x);
                float yy1 = fmaxf(wb.y, bx[j].y);
                float xx2 = fminf(wb.z, bx[j].z);
                float yy2 = fminf(wb.w, bx[j].w);
                float iw = fmaxf(xx2 - xx1, 0.f);
                float ih = fmaxf(yy2 - yy1, 0.f);
                float inter = iw * ih;
                float aj = (bx[j].z - bx[j].x) * (bx[j].w - bx[j].y);
                float denom = (warea + aj) - inter;
                bool supp = ((double)inter > (double)denom * SUPC) || (ia[j] == wa);
                if (supp) sc[j] = NEGF;
            }
        }
    }
    for (int z = k * 5 + t; z < TOPK * 5; z += OTHREADS) orow[z] = 0.f;
}

extern "C" void kernel_launch(void* const* d_in, const int* in_sizes, int n_in,
                              void* d_out, int out_size, void* d_ws, size_t ws_size,
                              hipStream_t stream) {
    const float* conf = (const float*)d_in[0];   // [B,A,C] f32
    const float* loc  = (const float*)d_in[1];   // [B,A,4] f32
    const float* anc  = (const float*)d_in[2];   // [A,4]   f32
    float* boxes = (float*)d_ws;

    decode_k<<<(NB * NA + 255) / 256, 256, 0, stream>>>(loc, anc, boxes);

    if (ws_size >= WS_FULL) {
        float* confT = (float*)((char*)d_ws + WS_CONFT_OFF);
        dim3 tg(NA / 32, 3, NB);
        transpose_k<<<tg, 256, 0, stream>>>(conf, confT, 0);
        nmsB2_k<<<NB * NC, 256, 0, stream>>>(confT, boxes, (float*)d_out, 0);
    } else if (ws_size >= WS_HALF) {
        float* confT = (float*)((char*)d_ws + WS_CONFT_OFF);
        for (int h = 0; h < 2; ++h) {
            dim3 tg(NA / 32, 3, 8);
            transpose_k<<<tg, 256, 0, stream>>>(conf, confT, h * 8);
            nmsB2_k<<<8 * NC, 256, 0, stream>>>(confT, boxes, (float*)d_out, h * 8);
        }
    } else {
        nms_old_k<<<NB * NC, OTHREADS, 0, stream>>>(conf, boxes, (float*)d_out);
    }
}

// Round 6
// 232.790 us; speedup vs baseline: 1.8759x; 1.0393x over previous
//
#include <hip/hip_runtime.h>
#include <math.h>

#define NB 16
#define NA 16384
#define NC 81
#define TOPK 50
#define TRC 4096                           // per-tranche candidate capacity
#define NEGF (-__builtin_inff())
#define SUPC 0.5000000298023223876953125   // 0.5 + 2^-25 (exact in double)

typedef unsigned long long ull;

// ws layout: boxes [NB*NA*4 f32] @0 (4 MiB), confT [nb*NC*NA f32] @4 MiB
#define WS_CONFT_OFF  ((size_t)4194304)
#define WS_FULL  (WS_CONFT_OFF + (size_t)NB * NC * NA * 4)   // 89,128,960
#define WS_HALF  (WS_CONFT_OFF + (size_t)8  * NC * NA * 4)   // 46,661,632

// ---------------- decode + clip (bit-verified rounds 1-5 — DO NOT TOUCH) ----------
__global__ __launch_bounds__(256) void decode_k(const float* __restrict__ loc,
                                                const float* __restrict__ anc,
                                                float* __restrict__ boxes) {
#pragma clang fp contract(off)
    int i = blockIdx.x * 256 + threadIdx.x;
    if (i >= NB * NA) return;
    int a = i & (NA - 1);
    float4 an = ((const float4*)anc)[a];
    float4 ld = ((const float4*)loc)[i];
    float cx = an.x + (ld.x * 0.1f) * an.z;
    float cy = an.y + (ld.y * 0.1f) * an.w;
    float w = an.z * (float)exp((double)(ld.z * 0.2f));
    float h = an.w * (float)exp((double)(ld.w * 0.2f));
    float x1 = cx - w * 0.5f;
    float y1 = cy - h * 0.5f;
    float x2 = x1 + w;
    float y2 = y1 + h;
    x1 = fminf(fmaxf(x1, 0.f), 1.f);
    y1 = fminf(fmaxf(y1, 0.f), 1.f);
    x2 = fminf(fmaxf(x2, 0.f), 1.f);
    y2 = fminf(fmaxf(y2, 0.f), 1.f);
    ((float4*)boxes)[i] = make_float4(x1, y1, x2, y2);
}

// ---------------- transpose v2: slab-contiguous read, coalesced row writes ----------
// Block = (b, 64-anchor slab): reads 64*81 floats CONTIGUOUS (float4), writes 81 rows
// of 256 B. Replaces round-5's strided-read 32x32 tile (dword-granular, ~1.9 TB/s).
#define TSLAB 64
__global__ __launch_bounds__(256) void transpose_k(const float* __restrict__ conf,
                                                   float* __restrict__ confT, int b0) {
    __shared__ float lin[TSLAB * NC];              // 20736 B
    const int bl = blockIdx.y;                     // local batch in this confT
    const int b = b0 + bl;
    const int a0 = blockIdx.x * TSLAB;
    const float4* src = (const float4*)(conf + ((size_t)b * NA + a0) * NC);
    const int t = threadIdx.x;
    for (int i = t; i < (TSLAB * NC) / 4; i += 256) {
        float4 v = src[i];
        lin[4 * i + 0] = v.x; lin[4 * i + 1] = v.y;
        lin[4 * i + 2] = v.z; lin[4 * i + 3] = v.w;
    }
    __syncthreads();
    const int x = t & 63, cg = t >> 6;
    float* dst = confT + (size_t)bl * NC * NA + a0 + x;
    for (int c = cg; c < NC; c += 4)               // 256 B per wave per row, coalesced
        dst[(size_t)c * NA] = lin[x * NC + c];     // LDS stride 81: 2-way conflict = free
}

// ---------------- bucket-sorted lazy greedy NMS v3: tranche-windowed, small LDS -------
__global__ __launch_bounds__(256, 8) void nmsB3_k(const float* __restrict__ confT,
                                                  const float* __restrict__ boxes,
                                                  float* __restrict__ out, int b0) {
#pragma clang fp contract(off)
    const int blk = blockIdx.x;
    const int bl = blk / NC, c = blk - bl * NC;
    const int b = b0 + bl;
    const int t = threadIdx.x;
    const int lane = t & 63, wv = t >> 6;

    __shared__ unsigned short s_ix[TRC];        // 8192 B
    __shared__ unsigned s_off[513];             // bucket starts (desc score order)
    __shared__ unsigned s_aux[512];             // hist -> cursors
    __shared__ float s_acc[TOPK][5];            // accepted x1,y1,x2,y2,area
    __shared__ float4 s_cbox[256];              // per-round candidate boxes
    __shared__ unsigned long long s_kill[4];
    __shared__ int s_ctrl[16];
    // ctrl: 0=nacc 1=tmp 2..5=chunk starts 6=chunk end 7=bptr 8=maxbucket
    //       9=bigE0 10=bigE1 11=mode 12=trLo 13=trHi

    const float* row = confT + ((size_t)bl * NC + c) * NA;
    const float4* row4 = (const float4*)row;
    const float4* bb = (const float4*)boxes + (size_t)b * NA;
    float* orow = out + ((size_t)b * NC + c) * (TOPK * 5);

    // --- histogram over 512 score buckets (top-9 mantissa bits; exp fixed in (.5,1)) ---
    for (int i = t; i < 512; i += 256) s_aux[i] = 0u;
    if (t == 0) { s_ctrl[0] = 0; s_ctrl[8] = 0; s_ctrl[12] = 0; }
    __syncthreads();
#pragma unroll 4
    for (int r = 0; r < 16; ++r) {
        float4 v4 = row4[t + 256 * r];
        if (v4.x > 0.5f) atomicAdd(&s_aux[511u - ((__float_as_uint(v4.x) >> 14) & 0x1FFu)], 1u);
        if (v4.y > 0.5f) atomicAdd(&s_aux[511u - ((__float_as_uint(v4.y) >> 14) & 0x1FFu)], 1u);
        if (v4.z > 0.5f) atomicAdd(&s_aux[511u - ((__float_as_uint(v4.z) >> 14) & 0x1FFu)], 1u);
        if (v4.w > 0.5f) atomicAdd(&s_aux[511u - ((__float_as_uint(v4.w) >> 14) & 0x1FFu)], 1u);
    }
    __syncthreads();
    for (int i = t; i < 512; i += 256) atomicMax(&s_ctrl[8], (int)s_aux[i]);
    // --- exclusive prefix -> s_off[0..512] (verified r3-r5 pattern) ---
    if (t == 0) s_off[0] = 0u;
    for (int i = t; i < 512; i += 256) s_off[i + 1] = s_aux[i];
    __syncthreads();
    for (int d = 1; d < 512; d <<= 1) {
        int i0 = 1 + t, i1 = 257 + t;
        unsigned v0 = (i0 - d >= 1) ? s_off[i0 - d] : 0u;
        unsigned v1 = (i1 - d >= 1) ? s_off[i1 - d] : 0u;
        __syncthreads();
        s_off[i0] += v0;
        s_off[i1] += v1;
        __syncthreads();
    }

    if (s_ctrl[8] <= TRC) {
        // =========================== fast path: tranche loop ===========================
        while (true) {
            if (t == 0) {
                int lo = s_ctrl[12];
                int hi = lo;
                while (hi < 512 && s_off[hi + 1] - s_off[lo] <= (unsigned)TRC) hi++;
                s_ctrl[13] = hi;
            }
            __syncthreads();
            const int trLo = s_ctrl[12], trHi = s_ctrl[13];
            const unsigned tbase = s_off[trLo], tend = s_off[trHi];
            if (tbase == tend) break;               // no candidates remain
            for (int i = trLo + t; i < trHi; i += 256) s_aux[i] = s_off[i] - tbase;
            __syncthreads();
            // --- scatter this tranche's anchor indices (row re-read is L3-hot) ---
#pragma unroll 4
            for (int r = 0; r < 16; ++r) {
                float4 v4 = row4[t + 256 * r];
                int a0i = 4 * (t + 256 * r);
                if (v4.x > 0.5f) { int bk = (int)(511u - ((__float_as_uint(v4.x) >> 14) & 0x1FFu)); if (bk >= trLo && bk < trHi) s_ix[atomicAdd(&s_aux[bk], 1u)] = (unsigned short)(a0i + 0); }
                if (v4.y > 0.5f) { int bk = (int)(511u - ((__float_as_uint(v4.y) >> 14) & 0x1FFu)); if (bk >= trLo && bk < trHi) s_ix[atomicAdd(&s_aux[bk], 1u)] = (unsigned short)(a0i + 1); }
                if (v4.z > 0.5f) { int bk = (int)(511u - ((__float_as_uint(v4.z) >> 14) & 0x1FFu)); if (bk >= trLo && bk < trHi) s_ix[atomicAdd(&s_aux[bk], 1u)] = (unsigned short)(a0i + 2); }
                if (v4.w > 0.5f) { int bk = (int)(511u - ((__float_as_uint(v4.w) >> 14) & 0x1FFu)); if (bk >= trLo && bk < trHi) s_ix[atomicAdd(&s_aux[bk], 1u)] = (unsigned short)(a0i + 3); }
            }
            if (t == 0) s_ctrl[7] = trLo;
            __syncthreads();

            // --- rounds: 4 bucket-aligned chunks of <=64, parallel test + serial resolve ---
            while (true) {
                if (t == 0) {
                    int bp = s_ctrl[7];
                    int mode;
                    if (bp >= trHi || s_off[bp] >= tend) {
                        mode = 2;
                    } else {
                        unsigned pos = s_off[bp] - tbase;
                        int bpl = bp;
                        unsigned q = pos;
                        for (int w = 0; w < 4; ++w) {
                            s_ctrl[2 + w] = (int)q;
                            while (bpl < trHi && (s_off[bpl + 1] - tbase - q) <= 64u) bpl++;
                            q = (bpl < trHi) ? s_off[bpl] - tbase : tend - tbase;
                        }
                        s_ctrl[6] = (int)q;
                        s_ctrl[7] = bpl;
                        mode = 0;
                        if (q == pos) {            // first bucket > 64 entries (rare)
                            mode = 1;
                            s_ctrl[9] = (int)pos;
                            s_ctrl[10] = (int)(s_off[bp + 1] - tbase);
                            s_ctrl[7] = bp + 1;
                        }
                    }
                    s_ctrl[11] = mode;
                }
                __syncthreads();
                const int mode = s_ctrl[11];
                if (mode == 2) break;
                const int nacc0 = s_ctrl[0];

                if (mode == 0) {
                    const unsigned q0 = (unsigned)s_ctrl[2 + wv];
                    const unsigned q1 = (unsigned)s_ctrl[3 + wv];
                    const int mw = (int)(q1 - q0);
                    const bool valid = lane < mw;
                    int ii = (int)q0 + lane; if (ii > TRC - 1) ii = TRC - 1;
                    int a = valid ? (int)s_ix[ii] : 0;
                    float4 bxv = bb[a];
                    if (!valid) bxv = make_float4(0.f, 0.f, 0.f, 0.f);
                    s_cbox[wv * 64 + lane] = bxv;
                    float mar = (bxv.z - bxv.x) * (bxv.w - bxv.y);
                    bool kill = !valid;
                    for (int j = 0; j < nacc0; ++j) {
                        float xx1 = fmaxf(s_acc[j][0], bxv.x), yy1 = fmaxf(s_acc[j][1], bxv.y);
                        float xx2 = fminf(s_acc[j][2], bxv.z), yy2 = fminf(s_acc[j][3], bxv.w);
                        float iw = fmaxf(xx2 - xx1, 0.f), ih = fmaxf(yy2 - yy1, 0.f);
                        float inter = iw * ih;
                        float den = (s_acc[j][4] + mar) - inter;
                        if ((double)inter > (double)den * SUPC) kill = true;
                    }
                    unsigned long long km = __ballot(kill);
                    if (lane == 0) s_kill[wv] = km;
                    __syncthreads();

                    if (wv == 0) {
                        int na = nacc0;
                        for (int cc = 0; cc < 4 && na < TOPK; ++cc) {
                            const unsigned e0 = (unsigned)s_ctrl[2 + cc];
                            const unsigned e1 = (unsigned)s_ctrl[3 + cc];
                            const int mc = (int)(e1 - e0);
                            if (mc <= 0) continue;
                            unsigned long long alive = ~s_kill[cc];
                            if (mc < 64) alive &= (1ull << mc) - 1ull;
                            int jj = (int)e0 + lane; if (jj > TRC - 1) jj = TRC - 1;
                            int aj = (lane < mc) ? (int)s_ix[jj] : 0;
                            float myscore = row[aj];               // L1/L2-hot gather
                            float4 mybx = s_cbox[cc * 64 + lane];
                            float mar2 = (mybx.z - mybx.x) * (mybx.w - mybx.y);
                            for (int j = nacc0; j < na && alive; ++j) {
                                float xx1 = fmaxf(s_acc[j][0], mybx.x), yy1 = fmaxf(s_acc[j][1], mybx.y);
                                float xx2 = fminf(s_acc[j][2], mybx.z), yy2 = fminf(s_acc[j][3], mybx.w);
                                float iw = fmaxf(xx2 - xx1, 0.f), ih = fmaxf(yy2 - yy1, 0.f);
                                float inter = iw * ih;
                                float den = (s_acc[j][4] + mar2) - inter;
                                bool sup = ((double)inter > (double)den * SUPC);
                                alive &= ~__ballot(sup);
                            }
                            unsigned long long mykey =
                                ((unsigned long long)__float_as_uint(myscore) << 32) |
                                (unsigned)(16383 - aj);
                            while (alive && na < TOPK) {
                                unsigned long long kk = ((alive >> lane) & 1ull) ? mykey : 0ull;
                                int src = lane;
                                for (int off = 32; off; off >>= 1) {
                                    unsigned long long ok = __shfl_xor(kk, off);
                                    int osrc = __shfl_xor(src, off);
                                    if (ok > kk) { kk = ok; src = osrc; }
                                }
                                float4 wb = s_cbox[cc * 64 + src];
                                float wscore = __shfl(myscore, src);
                                float war = (wb.z - wb.x) * (wb.w - wb.y);
                                if (lane == 0) {
                                    orow[na * 5 + 0] = wscore;
                                    orow[na * 5 + 1] = wb.x; orow[na * 5 + 2] = wb.y;
                                    orow[na * 5 + 3] = wb.z; orow[na * 5 + 4] = wb.w;
                                    s_acc[na][0] = wb.x; s_acc[na][1] = wb.y;
                                    s_acc[na][2] = wb.z; s_acc[na][3] = wb.w;
                                    s_acc[na][4] = war;
                                }
                                na++;
                                alive &= ~(1ull << src);
                                if (alive) {
                                    float xx1 = fmaxf(wb.x, mybx.x), yy1 = fmaxf(wb.y, mybx.y);
                                    float xx2 = fminf(wb.z, mybx.z), yy2 = fminf(wb.w, mybx.w);
                                    float iw = fmaxf(xx2 - xx1, 0.f), ih = fmaxf(yy2 - yy1, 0.f);
                                    float inter = iw * ih;
                                    float den = (war + mar2) - inter;
                                    bool sup = ((double)inter > (double)den * SUPC);
                                    alive &= ~__ballot(sup);
                                }
                            }
                        }
                        if (lane == 0) s_ctrl[0] = na;
                    }
                    __syncthreads();
                } else {
                    // big-bucket (>64 in one bucket, <=TRC): wave-0 extraction
                    const int e0 = s_ctrl[9], e1 = s_ctrl[10];
                    if (wv == 0) {
                        int na = s_ctrl[0];
                        while (na < TOPK) {
                            unsigned long long bk = 0ull; int bpos = 0;
                            for (int i = e0 + lane; i < e1; i += 64) {
                                int av = (int)s_ix[i];
                                if (av != 0xFFFF) {
                                    float v = row[av];
                                    unsigned long long k =
                                        ((unsigned long long)__float_as_uint(v) << 32) |
                                        (unsigned)(16383 - av);
                                    if (k > bk) { bk = k; bpos = i; }
                                }
                            }
                            for (int off = 32; off; off >>= 1) {
                                unsigned long long ok = __shfl_xor(bk, off);
                                int op = __shfl_xor(bpos, off);
                                if (ok > bk) { bk = ok; bpos = op; }
                            }
                            if (bk == 0ull) break;
                            int a = (int)s_ix[bpos];
                            float wscore = __uint_as_float((unsigned)(bk >> 32));
                            if (lane == 0) s_ix[bpos] = 0xFFFFu;     // consume
                            float4 wb = bb[a];
                            float war = (wb.z - wb.x) * (wb.w - wb.y);
                            bool sup = false;
                            if (lane < na) {
                                float xx1 = fmaxf(s_acc[lane][0], wb.x), yy1 = fmaxf(s_acc[lane][1], wb.y);
                                float xx2 = fminf(s_acc[lane][2], wb.z), yy2 = fminf(s_acc[lane][3], wb.w);
                                float iw = fmaxf(xx2 - xx1, 0.f), ih = fmaxf(yy2 - yy1, 0.f);
                                float inter = iw * ih;
                                float den = (s_acc[lane][4] + war) - inter;
                                sup = ((double)inter > (double)den * SUPC);
                            }
                            if (__ballot(sup) == 0ull) {
                                if (lane == 0) {
                                    orow[na * 5 + 0] = wscore;
                                    orow[na * 5 + 1] = wb.x; orow[na * 5 + 2] = wb.y;
                                    orow[na * 5 + 3] = wb.z; orow[na * 5 + 4] = wb.w;
                                    s_acc[na][0] = wb.x; s_acc[na][1] = wb.y;
                                    s_acc[na][2] = wb.z; s_acc[na][3] = wb.w;
                                    s_acc[na][4] = war;
                                }
                                na++;
                            }
                        }
                        if (lane == 0) s_ctrl[0] = na;
                    }
                    __syncthreads();
                }
                if (s_ctrl[0] >= TOPK) break;
            }
            // --- tranche done ---
            if (s_ctrl[0] >= TOPK || trHi >= 512) break;
            if (t == 0) s_ctrl[12] = trHi;
            __syncthreads();
        }
    } else {
        // ========== exact windowed path (single bucket > TRC; ≈ never) ==========
        float hi = 1.0f, delta = 0.02f;
        while (true) {
            if (s_ctrl[0] >= TOPK || hi <= 0.5f) break;
            float lo = fmaxf(hi - delta, 0.5f);
            if (t == 0) s_ctrl[1] = 0;
            __syncthreads();
            for (int r = 0; r < 16; ++r) {
                float4 v4 = row4[t + 256 * r];
                int a0i = 4 * (t + 256 * r);
                if (v4.x > lo && v4.x <= hi) { int p = atomicAdd(&s_ctrl[1], 1); if (p < TRC) s_ix[p] = (unsigned short)(a0i + 0); }
                if (v4.y > lo && v4.y <= hi) { int p = atomicAdd(&s_ctrl[1], 1); if (p < TRC) s_ix[p] = (unsigned short)(a0i + 1); }
                if (v4.z > lo && v4.z <= hi) { int p = atomicAdd(&s_ctrl[1], 1); if (p < TRC) s_ix[p] = (unsigned short)(a0i + 2); }
                if (v4.w > lo && v4.w <= hi) { int p = atomicAdd(&s_ctrl[1], 1); if (p < TRC) s_ix[p] = (unsigned short)(a0i + 3); }
            }
            __syncthreads();
            int m = s_ctrl[1];
            if (m > TRC) { delta *= 0.5f; continue; }
            if (wv == 0) {
                int na = s_ctrl[0];
                while (na < TOPK) {
                    unsigned long long bk = 0ull; int bpos = 0;
                    for (int i = lane; i < m; i += 64) {
                        int av = (int)s_ix[i];
                        if (av != 0xFFFF) {
                            float v = row[av];
                            unsigned long long k =
                                ((unsigned long long)__float_as_uint(v) << 32) |
                                (unsigned)(16383 - av);
                            if (k > bk) { bk = k; bpos = i; }
                        }
                    }
                    for (int off = 32; off; off >>= 1) {
                        unsigned long long ok = __shfl_xor(bk, off);
                        int op = __shfl_xor(bpos, off);
                        if (ok > bk) { bk = ok; bpos = op; }
                    }
                    if (bk == 0ull) break;
                    int a = (int)s_ix[bpos];
                    float wscore = __uint_as_float((unsigned)(bk >> 32));
                    if (lane == 0) s_ix[bpos] = 0xFFFFu;
                    float4 wb = bb[a];
                    float war = (wb.z - wb.x) * (wb.w - wb.y);
                    bool sup = false;
                    if (lane < na) {
                        float xx1 = fmaxf(s_acc[lane][0], wb.x), yy1 = fmaxf(s_acc[lane][1], wb.y);
                        float xx2 = fminf(s_acc[lane][2], wb.z), yy2 = fminf(s_acc[lane][3], wb.w);
                        float iw = fmaxf(xx2 - xx1, 0.f), ih = fmaxf(yy2 - yy1, 0.f);
                        float inter = iw * ih;
                        float den = (s_acc[lane][4] + war) - inter;
                        sup = ((double)inter > (double)den * SUPC);
                    }
                    if (__ballot(sup) == 0ull) {
                        if (lane == 0) {
                            orow[na * 5 + 0] = wscore;
                            orow[na * 5 + 1] = wb.x; orow[na * 5 + 2] = wb.y;
                            orow[na * 5 + 3] = wb.z; orow[na * 5 + 4] = wb.w;
                            s_acc[na][0] = wb.x; s_acc[na][1] = wb.y;
                            s_acc[na][2] = wb.z; s_acc[na][3] = wb.w;
                            s_acc[na][4] = war;
                        }
                        na++;
                    }
                }
                if (lane == 0) s_ctrl[0] = na;
            }
            __syncthreads();
            hi = lo;
        }
    }

    __syncthreads();
    const int naF = s_ctrl[0];
    for (int z = naF * 5 + t; z < TOPK * 5; z += 256) orow[z] = 0.f;
}

// ============== round-1 fallback (only if ws too small for fast paths) ==============
#define OTHREADS 1024
#define OCAP 10240
#define OJMAX 10

__global__ __launch_bounds__(OTHREADS) void nms_old_k(const float* __restrict__ conf,
                                                      const float* __restrict__ boxes,
                                                      float* __restrict__ out) {
#pragma clang fp contract(off)
    const int blk = blockIdx.x;
    const int b = blk / NC, c = blk - b * NC;
    const int t = threadIdx.x;
    const int lane = t & 63, wid = t >> 6;
    __shared__ float s_val[OCAP];
    __shared__ unsigned short s_idx[OCAP];
    __shared__ float s_ps[2][16];
    __shared__ int s_pa[2][16];
    __shared__ int s_n;
    if (t == 0) s_n = 0;
    __syncthreads();
    const float* cp = conf + ((size_t)b * NA) * NC + c;
    float v[NA / OTHREADS];
#pragma unroll
    for (int r = 0; r < NA / OTHREADS; ++r)
        v[r] = cp[(size_t)(r * OTHREADS + t) * NC];
#pragma unroll
    for (int r = 0; r < NA / OTHREADS; ++r) {
        int a = r * OTHREADS + t;
        bool alive = v[r] > 0.5f;
        unsigned long long m = __ballot(alive);
        int cnt = __popcll(m);
        int base = 0;
        if (lane == 0 && cnt) base = atomicAdd(&s_n, cnt);
        base = __shfl(base, 0);
        if (alive) {
            int p = base + __popcll(m & ((1ull << lane) - 1));
            if (p < OCAP) { s_val[p] = v[r]; s_idx[p] = (unsigned short)a; }
        }
    }
    __syncthreads();
    int n = s_n; if (n > OCAP) n = OCAP;
    const int jn = (n + OTHREADS - 1) / OTHREADS;
    const float4* bb = (const float4*)boxes + (size_t)b * NA;
    float sc[OJMAX]; float4 bx[OJMAX]; int ia[OJMAX];
#pragma unroll
    for (int j = 0; j < OJMAX; ++j) {
        sc[j] = NEGF; ia[j] = 0x7fffffff; bx[j] = make_float4(0.f, 0.f, 0.f, 0.f);
        int p = j * OTHREADS + t;
        if (p < n) { sc[j] = s_val[p]; ia[j] = (int)s_idx[p]; bx[j] = bb[ia[j]]; }
    }
    float* orow = out + (size_t)blk * (TOPK * 5);
    int k = 0;
    for (; k < TOPK; ++k) {
        float ms = NEGF; int ma = 0x7fffffff;
#pragma unroll
        for (int j = 0; j < OJMAX; ++j) {
            if (j < jn) {
                bool better = (sc[j] > ms) || (sc[j] == ms && ia[j] < ma);
                ms = better ? sc[j] : ms;
                ma = better ? ia[j] : ma;
            }
        }
#pragma unroll
        for (int off = 32; off; off >>= 1) {
            float os = __shfl_xor(ms, off);
            int oa = __shfl_xor(ma, off);
            if (os > ms || (os == ms && oa < ma)) { ms = os; ma = oa; }
        }
        int pb = k & 1;
        if (lane == 0) { s_ps[pb][wid] = ms; s_pa[pb][wid] = ma; }
        __syncthreads();
        float wsv = NEGF; int wa = 0x7fffffff;
#pragma unroll
        for (int w = 0; w < 16; ++w) {
            float os = s_ps[pb][w]; int oa = s_pa[pb][w];
            if (os > wsv || (os == wsv && oa < wa)) { wsv = os; wa = oa; }
        }
        if (!(wsv > NEGF)) break;
        float4 wb = bb[wa];
        float warea = (wb.z - wb.x) * (wb.w - wb.y);
        if (t == 0) {
            orow[k * 5 + 0] = wsv;
            orow[k * 5 + 1] = wb.x; orow[k * 5 + 2] = wb.y;
            orow[k * 5 + 3] = wb.z; orow[k * 5 + 4] = wb.w;
        }
#pragma unroll
        for (int j = 0; j < OJMAX; ++j) {
            if (j < jn) {
                float xx1 = fmaxf(wb.x, bx[j].x);
                float yy1 = fmaxf(wb.y, bx[j].y);
                float xx2 = fminf(wb.z, bx[j].z);
                float yy2 = fminf(wb.w, bx[j].w);
                float iw = fmaxf(xx2 - xx1, 0.f);
                float ih = fmaxf(yy2 - yy1, 0.f);
                float inter = iw * ih;
                float aj = (bx[j].z - bx[j].x) * (bx[j].w - bx[j].y);
                float denom = (warea + aj) - inter;
                bool supp = ((double)inter > (double)denom * SUPC) || (ia[j] == wa);
                if (supp) sc[j] = NEGF;
            }
        }
    }
    for (int z = k * 5 + t; z < TOPK * 5; z += OTHREADS) orow[z] = 0.f;
}

extern "C" void kernel_launch(void* const* d_in, const int* in_sizes, int n_in,
                              void* d_out, int out_size, void* d_ws, size_t ws_size,
                              hipStream_t stream) {
    const float* conf = (const float*)d_in[0];   // [B,A,C] f32
    const float* loc  = (const float*)d_in[1];   // [B,A,4] f32
    const float* anc  = (const float*)d_in[2];   // [A,4]   f32
    float* boxes = (float*)d_ws;

    decode_k<<<(NB * NA + 255) / 256, 256, 0, stream>>>(loc, anc, boxes);

    if (ws_size >= WS_FULL) {
        float* confT = (float*)((char*)d_ws + WS_CONFT_OFF);
        dim3 tg(NA / TSLAB, NB);
        transpose_k<<<tg, 256, 0, stream>>>(conf, confT, 0);
        nmsB3_k<<<NB * NC, 256, 0, stream>>>(confT, boxes, (float*)d_out, 0);
    } else if (ws_size >= WS_HALF) {
        float* confT = (float*)((char*)d_ws + WS_CONFT_OFF);
        for (int h = 0; h < 2; ++h) {
            dim3 tg(NA / TSLAB, 8);
            transpose_k<<<tg, 256, 0, stream>>>(conf, confT, h * 8);
            nmsB3_k<<<8 * NC, 256, 0, stream>>>(confT, boxes, (float*)d_out, h * 8);
        }
    } else {
        nms_old_k<<<NB * NC, OTHREADS, 0, stream>>>(conf, boxes, (float*)d_out);
    }
}

// Round 7
// 231.136 us; speedup vs baseline: 1.8893x; 1.0072x over previous
//
#include <hip/hip_runtime.h>
#include <math.h>

#define NB 16
#define NA 16384
#define NC 81
#define TOPK 50
#define TRC 4096                           // per-tranche candidate capacity
#define NEGF (-__builtin_inff())
#define SUPC 0.5000000298023223876953125   // 0.5 + 2^-25 (exact in double)

typedef unsigned long long ull;

// ws layout: boxes [NB*NA*4 f32] @0 (4 MiB), confT16 [NB*NC*NA u16] @4 MiB (42.5 MB)
#define WS_CONFT_OFF  ((size_t)4194304)
#define WS_FULL  (WS_CONFT_OFF + (size_t)NB * NC * NA * 2)   // 46,661,632

// ---------------- decode + clip (bit-verified rounds 1-6 — DO NOT TOUCH) ----------
__global__ __launch_bounds__(256) void decode_k(const float* __restrict__ loc,
                                                const float* __restrict__ anc,
                                                float* __restrict__ boxes) {
#pragma clang fp contract(off)
    int i = blockIdx.x * 256 + threadIdx.x;
    if (i >= NB * NA) return;
    int a = i & (NA - 1);
    float4 an = ((const float4*)anc)[a];
    float4 ld = ((const float4*)loc)[i];
    float cx = an.x + (ld.x * 0.1f) * an.z;
    float cy = an.y + (ld.y * 0.1f) * an.w;
    float w = an.z * (float)exp((double)(ld.z * 0.2f));
    float h = an.w * (float)exp((double)(ld.w * 0.2f));
    float x1 = cx - w * 0.5f;
    float y1 = cy - h * 0.5f;
    float x2 = x1 + w;
    float y2 = y1 + h;
    x1 = fminf(fmaxf(x1, 0.f), 1.f);
    y1 = fminf(fmaxf(y1, 0.f), 1.f);
    x2 = fminf(fmaxf(x2, 0.f), 1.f);
    y2 = fminf(fmaxf(y2, 0.f), 1.f);
    ((float4*)boxes)[i] = make_float4(x1, y1, x2, y2);
}

// encode score -> 16-bit code: 9-bit DESCENDING bucket for v in (0.5,1), else 0xFFFF
__device__ __forceinline__ unsigned short enc_code(float v) {
    unsigned short e = 0xFFFFu;
    if (v > 0.5f) e = (unsigned short)(511u - ((__float_as_uint(v) >> 14) & 0x1FFu));
    return e;
}

// ---------------- transpose v3: conf f32 [B,A,C] -> confT16 u16 codes [B,C,A] --------
// Block = (b, 256-anchor slab): 83 KB contiguous float4 read, convert in-register,
// per-class 512 B write runs (u64 stores). Halves volume AND doubles burst size vs
// the f32 transpose that plateaued at ~1.3 TB/s on 256 B scattered granules.
#define TSLAB 256
__global__ __launch_bounds__(256) void transq_k(const float* __restrict__ conf,
                                                unsigned short* __restrict__ confT) {
    __shared__ unsigned short code[TSLAB * NC];    // [c][a] : c*256+a, 41472 B
    const int b = blockIdx.y;
    const int slab = blockIdx.x;
    const float4* src = (const float4*)(conf + ((size_t)b * NA + (size_t)slab * TSLAB) * NC);
    const int t = threadIdx.x;
    for (int i = t; i < (TSLAB * NC) / 4; i += 256) {
        float4 v = src[i];
        unsigned f = 4u * (unsigned)i;
        unsigned a = f / (unsigned)NC;             // magic-mul div
        unsigned c = f - a * (unsigned)NC;
        code[c * TSLAB + a] = enc_code(v.x);
        if (++c == NC) { c = 0; ++a; }
        code[c * TSLAB + a] = enc_code(v.y);
        if (++c == NC) { c = 0; ++a; }
        code[c * TSLAB + a] = enc_code(v.z);
        if (++c == NC) { c = 0; ++a; }
        code[c * TSLAB + a] = enc_code(v.w);
    }
    __syncthreads();
    const int lane = t & 63, wv = t >> 6;
    for (int c = wv; c < NC; c += 4) {             // 64 lanes x 8 B = 512 B per class
        ull v = *(const ull*)&code[c * TSLAB + lane * 4];
        *(ull*)(confT + ((size_t)b * NC + c) * NA + (size_t)slab * TSLAB + lane * 4) = v;
    }
}

// ---------------- bucket-sorted lazy greedy NMS v4: u16-code rows + conf gathers ------
__global__ __launch_bounds__(256, 8) void nmsB4_k(const unsigned short* __restrict__ confT,
                                                  const float* __restrict__ conf,
                                                  const float* __restrict__ boxes,
                                                  float* __restrict__ out) {
#pragma clang fp contract(off)
    const int blk = blockIdx.x;
    const int b = blk / NC, c = blk - b * NC;
    const int t = threadIdx.x;
    const int lane = t & 63, wv = t >> 6;

    __shared__ unsigned short s_ix[TRC];        // 8192 B
    __shared__ unsigned s_off[513];             // bucket starts (desc score order)
    __shared__ unsigned s_aux[512];             // hist -> cursors
    __shared__ float s_acc[TOPK][5];            // accepted x1,y1,x2,y2,area
    __shared__ float4 s_cbox[256];              // per-round candidate boxes
    __shared__ unsigned long long s_kill[4];
    __shared__ int s_ctrl[16];
    // ctrl: 0=nacc 1=tmp 2..5=chunk starts 6=chunk end 7=bptr 8=maxbucket
    //       9=bigE0 10=bigE1 11=mode 12=trLo 13=trHi

    const uint4* row8 = (const uint4*)(confT + ((size_t)b * NC + c) * NA); // 8 codes/16B
    const float* cp = conf + ((size_t)b * NA) * NC + c;   // exact scores: cp[a*NC], L3-hot
    const float4* bb = (const float4*)boxes + (size_t)b * NA;
    float* orow = out + ((size_t)b * NC + c) * (TOPK * 5);

    // --- histogram over 512 buckets from u16 codes ---
    for (int i = t; i < 512; i += 256) s_aux[i] = 0u;
    if (t == 0) { s_ctrl[0] = 0; s_ctrl[8] = 0; s_ctrl[12] = 0; }
    __syncthreads();
#pragma unroll
    for (int r = 0; r < 8; ++r) {
        uint4 q = row8[t + 256 * r];
        unsigned w;
        w = q.x; if ((w & 0xFFFFu) != 0xFFFFu) atomicAdd(&s_aux[w & 0xFFFFu], 1u);
                 if ((w >> 16)     != 0xFFFFu) atomicAdd(&s_aux[w >> 16], 1u);
        w = q.y; if ((w & 0xFFFFu) != 0xFFFFu) atomicAdd(&s_aux[w & 0xFFFFu], 1u);
                 if ((w >> 16)     != 0xFFFFu) atomicAdd(&s_aux[w >> 16], 1u);
        w = q.z; if ((w & 0xFFFFu) != 0xFFFFu) atomicAdd(&s_aux[w & 0xFFFFu], 1u);
                 if ((w >> 16)     != 0xFFFFu) atomicAdd(&s_aux[w >> 16], 1u);
        w = q.w; if ((w & 0xFFFFu) != 0xFFFFu) atomicAdd(&s_aux[w & 0xFFFFu], 1u);
                 if ((w >> 16)     != 0xFFFFu) atomicAdd(&s_aux[w >> 16], 1u);
    }
    __syncthreads();
    for (int i = t; i < 512; i += 256) atomicMax(&s_ctrl[8], (int)s_aux[i]);
    // --- exclusive prefix -> s_off[0..512] (verified r3-r6 pattern) ---
    if (t == 0) s_off[0] = 0u;
    for (int i = t; i < 512; i += 256) s_off[i + 1] = s_aux[i];
    __syncthreads();
    for (int d = 1; d < 512; d <<= 1) {
        int i0 = 1 + t, i1 = 257 + t;
        unsigned v0 = (i0 - d >= 1) ? s_off[i0 - d] : 0u;
        unsigned v1 = (i1 - d >= 1) ? s_off[i1 - d] : 0u;
        __syncthreads();
        s_off[i0] += v0;
        s_off[i1] += v1;
        __syncthreads();
    }

    if (s_ctrl[8] <= TRC) {
        // =========================== fast path: tranche loop ===========================
        while (true) {
            if (t == 0) {
                int lo = s_ctrl[12];
                int hi = lo;
                while (hi < 512 && s_off[hi + 1] - s_off[lo] <= (unsigned)TRC) hi++;
                s_ctrl[13] = hi;
            }
            __syncthreads();
            const int trLo = s_ctrl[12], trHi = s_ctrl[13];
            const unsigned tbase = s_off[trLo], tend = s_off[trHi];
            if (tbase == tend) break;               // no candidates remain
            for (int i = trLo + t; i < trHi; i += 256) s_aux[i] = s_off[i] - tbase;
            __syncthreads();
            // --- scatter tranche's anchor indices (code row is L1/L2-hot, 32 KB) ---
#pragma unroll
            for (int r = 0; r < 8; ++r) {
                uint4 q = row8[t + 256 * r];
                int a0i = 8 * (t + 256 * r);
                unsigned w; int bk;
                w = q.x;
                bk = (int)(w & 0xFFFFu); if (bk >= trLo && bk < trHi) s_ix[atomicAdd(&s_aux[bk], 1u)] = (unsigned short)(a0i + 0);
                bk = (int)(w >> 16);     if (bk >= trLo && bk < trHi) s_ix[atomicAdd(&s_aux[bk], 1u)] = (unsigned short)(a0i + 1);
                w = q.y;
                bk = (int)(w & 0xFFFFu); if (bk >= trLo && bk < trHi) s_ix[atomicAdd(&s_aux[bk], 1u)] = (unsigned short)(a0i + 2);
                bk = (int)(w >> 16);     if (bk >= trLo && bk < trHi) s_ix[atomicAdd(&s_aux[bk], 1u)] = (unsigned short)(a0i + 3);
                w = q.z;
                bk = (int)(w & 0xFFFFu); if (bk >= trLo && bk < trHi) s_ix[atomicAdd(&s_aux[bk], 1u)] = (unsigned short)(a0i + 4);
                bk = (int)(w >> 16);     if (bk >= trLo && bk < trHi) s_ix[atomicAdd(&s_aux[bk], 1u)] = (unsigned short)(a0i + 5);
                w = q.w;
                bk = (int)(w & 0xFFFFu); if (bk >= trLo && bk < trHi) s_ix[atomicAdd(&s_aux[bk], 1u)] = (unsigned short)(a0i + 6);
                bk = (int)(w >> 16);     if (bk >= trLo && bk < trHi) s_ix[atomicAdd(&s_aux[bk], 1u)] = (unsigned short)(a0i + 7);
            }
            if (t == 0) s_ctrl[7] = trLo;
            __syncthreads();

            // --- rounds: 4 bucket-aligned chunks of <=64, parallel test + serial resolve ---
            while (true) {
                if (t == 0) {
                    int bp = s_ctrl[7];
                    int mode;
                    if (bp >= trHi || s_off[bp] >= tend) {
                        mode = 2;
                    } else {
                        unsigned pos = s_off[bp] - tbase;
                        int bpl = bp;
                        unsigned q = pos;
                        for (int w = 0; w < 4; ++w) {
                            s_ctrl[2 + w] = (int)q;
                            while (bpl < trHi && (s_off[bpl + 1] - tbase - q) <= 64u) bpl++;
                            q = (bpl < trHi) ? s_off[bpl] - tbase : tend - tbase;
                        }
                        s_ctrl[6] = (int)q;
                        s_ctrl[7] = bpl;
                        mode = 0;
                        if (q == pos) {            // first bucket > 64 entries (rare)
                            mode = 1;
                            s_ctrl[9] = (int)pos;
                            s_ctrl[10] = (int)(s_off[bp + 1] - tbase);
                            s_ctrl[7] = bp + 1;
                        }
                    }
                    s_ctrl[11] = mode;
                }
                __syncthreads();
                const int mode = s_ctrl[11];
                if (mode == 2) break;
                const int nacc0 = s_ctrl[0];

                if (mode == 0) {
                    const unsigned q0 = (unsigned)s_ctrl[2 + wv];
                    const unsigned q1 = (unsigned)s_ctrl[3 + wv];
                    const int mw = (int)(q1 - q0);
                    const bool valid = lane < mw;
                    int ii = (int)q0 + lane; if (ii > TRC - 1) ii = TRC - 1;
                    int a = valid ? (int)s_ix[ii] : 0;
                    float4 bxv = bb[a];
                    if (!valid) bxv = make_float4(0.f, 0.f, 0.f, 0.f);
                    s_cbox[wv * 64 + lane] = bxv;
                    float mar = (bxv.z - bxv.x) * (bxv.w - bxv.y);
                    bool kill = !valid;
                    for (int j = 0; j < nacc0; ++j) {
                        float xx1 = fmaxf(s_acc[j][0], bxv.x), yy1 = fmaxf(s_acc[j][1], bxv.y);
                        float xx2 = fminf(s_acc[j][2], bxv.z), yy2 = fminf(s_acc[j][3], bxv.w);
                        float iw = fmaxf(xx2 - xx1, 0.f), ih = fmaxf(yy2 - yy1, 0.f);
                        float inter = iw * ih;
                        float den = (s_acc[j][4] + mar) - inter;
                        if ((double)inter > (double)den * SUPC) kill = true;
                    }
                    unsigned long long km = __ballot(kill);
                    if (lane == 0) s_kill[wv] = km;
                    __syncthreads();

                    if (wv == 0) {
                        int na = nacc0;
                        for (int cc = 0; cc < 4 && na < TOPK; ++cc) {
                            const unsigned e0 = (unsigned)s_ctrl[2 + cc];
                            const unsigned e1 = (unsigned)s_ctrl[3 + cc];
                            const int mc = (int)(e1 - e0);
                            if (mc <= 0) continue;
                            unsigned long long alive = ~s_kill[cc];
                            if (mc < 64) alive &= (1ull << mc) - 1ull;
                            int jj = (int)e0 + lane; if (jj > TRC - 1) jj = TRC - 1;
                            int aj = (lane < mc) ? (int)s_ix[jj] : 0;
                            float myscore = cp[(size_t)aj * NC];       // exact f32, L3-hot
                            float4 mybx = s_cbox[cc * 64 + lane];
                            float mar2 = (mybx.z - mybx.x) * (mybx.w - mybx.y);
                            for (int j = nacc0; j < na && alive; ++j) {
                                float xx1 = fmaxf(s_acc[j][0], mybx.x), yy1 = fmaxf(s_acc[j][1], mybx.y);
                                float xx2 = fminf(s_acc[j][2], mybx.z), yy2 = fminf(s_acc[j][3], mybx.w);
                                float iw = fmaxf(xx2 - xx1, 0.f), ih = fmaxf(yy2 - yy1, 0.f);
                                float inter = iw * ih;
                                float den = (s_acc[j][4] + mar2) - inter;
                                bool sup = ((double)inter > (double)den * SUPC);
                                alive &= ~__ballot(sup);
                            }
                            unsigned long long mykey =
                                ((unsigned long long)__float_as_uint(myscore) << 32) |
                                (unsigned)(16383 - aj);
                            while (alive && na < TOPK) {
                                unsigned long long kk = ((alive >> lane) & 1ull) ? mykey : 0ull;
                                int src = lane;
                                for (int off = 32; off; off >>= 1) {
                                    unsigned long long ok = __shfl_xor(kk, off);
                                    int osrc = __shfl_xor(src, off);
                                    if (ok > kk) { kk = ok; src = osrc; }
                                }
                                float4 wb = s_cbox[cc * 64 + src];
                                float wscore = __shfl(myscore, src);
                                float war = (wb.z - wb.x) * (wb.w - wb.y);
                                if (lane == 0) {
                                    orow[na * 5 + 0] = wscore;
                                    orow[na * 5 + 1] = wb.x; orow[na * 5 + 2] = wb.y;
                                    orow[na * 5 + 3] = wb.z; orow[na * 5 + 4] = wb.w;
                                    s_acc[na][0] = wb.x; s_acc[na][1] = wb.y;
                                    s_acc[na][2] = wb.z; s_acc[na][3] = wb.w;
                                    s_acc[na][4] = war;
                                }
                                na++;
                                alive &= ~(1ull << src);
                                if (alive) {
                                    float xx1 = fmaxf(wb.x, mybx.x), yy1 = fmaxf(wb.y, mybx.y);
                                    float xx2 = fminf(wb.z, mybx.z), yy2 = fminf(wb.w, mybx.w);
                                    float iw = fmaxf(xx2 - xx1, 0.f), ih = fmaxf(yy2 - yy1, 0.f);
                                    float inter = iw * ih;
                                    float den = (war + mar2) - inter;
                                    bool sup = ((double)inter > (double)den * SUPC);
                                    alive &= ~__ballot(sup);
                                }
                            }
                        }
                        if (lane == 0) s_ctrl[0] = na;
                    }
                    __syncthreads();
                } else {
                    // big-bucket (>64 in one bucket, <=TRC): wave-0 extraction
                    const int e0 = s_ctrl[9], e1 = s_ctrl[10];
                    if (wv == 0) {
                        int na = s_ctrl[0];
                        while (na < TOPK) {
                            unsigned long long bk = 0ull; int bpos = 0;
                            for (int i = e0 + lane; i < e1; i += 64) {
                                int av = (int)s_ix[i];
                                if (av != 0xFFFF) {
                                    float v = cp[(size_t)av * NC];
                                    unsigned long long k =
                                        ((unsigned long long)__float_as_uint(v) << 32) |
                                        (unsigned)(16383 - av);
                                    if (k > bk) { bk = k; bpos = i; }
                                }
                            }
                            for (int off = 32; off; off >>= 1) {
                                unsigned long long ok = __shfl_xor(bk, off);
                                int op = __shfl_xor(bpos, off);
                                if (ok > bk) { bk = ok; bpos = op; }
                            }
                            if (bk == 0ull) break;
                            int a = (int)s_ix[bpos];
                            float wscore = __uint_as_float((unsigned)(bk >> 32));
                            if (lane == 0) s_ix[bpos] = 0xFFFFu;     // consume
                            float4 wb = bb[a];
                            float war = (wb.z - wb.x) * (wb.w - wb.y);
                            bool sup = false;
                            if (lane < na) {
                                float xx1 = fmaxf(s_acc[lane][0], wb.x), yy1 = fmaxf(s_acc[lane][1], wb.y);
                                float xx2 = fminf(s_acc[lane][2], wb.z), yy2 = fminf(s_acc[lane][3], wb.w);
                                float iw = fmaxf(xx2 - xx1, 0.f), ih = fmaxf(yy2 - yy1, 0.f);
                                float inter = iw * ih;
                                float den = (s_acc[lane][4] + war) - inter;
                                sup = ((double)inter > (double)den * SUPC);
                            }
                            if (__ballot(sup) == 0ull) {
                                if (lane == 0) {
                                    orow[na * 5 + 0] = wscore;
                                    orow[na * 5 + 1] = wb.x; orow[na * 5 + 2] = wb.y;
                                    orow[na * 5 + 3] = wb.z; orow[na * 5 + 4] = wb.w;
                                    s_acc[na][0] = wb.x; s_acc[na][1] = wb.y;
                                    s_acc[na][2] = wb.z; s_acc[na][3] = wb.w;
                                    s_acc[na][4] = war;
                                }
                                na++;
                            }
                        }
                        if (lane == 0) s_ctrl[0] = na;
                    }
                    __syncthreads();
                }
                if (s_ctrl[0] >= TOPK) break;
            }
            // --- tranche done ---
            if (s_ctrl[0] >= TOPK || trHi >= 512) break;
            if (t == 0) s_ctrl[12] = trHi;
            __syncthreads();
        }
    } else {
        // ===== exact windowed path (single bucket > TRC; P~0): strided conf scan =====
        float hi = 1.0f, delta = 0.02f;
        while (true) {
            if (s_ctrl[0] >= TOPK || hi <= 0.5f) break;
            float lo = fmaxf(hi - delta, 0.5f);
            if (t == 0) s_ctrl[1] = 0;
            __syncthreads();
            for (int a = t; a < NA; a += 256) {
                float v = cp[(size_t)a * NC];
                if (v > lo && v <= hi) {
                    int p = atomicAdd(&s_ctrl[1], 1);
                    if (p < TRC) s_ix[p] = (unsigned short)a;
                }
            }
            __syncthreads();
            int m = s_ctrl[1];
            if (m > TRC) { delta *= 0.5f; continue; }
            if (wv == 0) {
                int na = s_ctrl[0];
                while (na < TOPK) {
                    unsigned long long bk = 0ull; int bpos = 0;
                    for (int i = lane; i < m; i += 64) {
                        int av = (int)s_ix[i];
                        if (av != 0xFFFF) {
                            float v = cp[(size_t)av * NC];
                            unsigned long long k =
                                ((unsigned long long)__float_as_uint(v) << 32) |
                                (unsigned)(16383 - av);
                            if (k > bk) { bk = k; bpos = i; }
                        }
                    }
                    for (int off = 32; off; off >>= 1) {
                        unsigned long long ok = __shfl_xor(bk, off);
                        int op = __shfl_xor(bpos, off);
                        if (ok > bk) { bk = ok; bpos = op; }
                    }
                    if (bk == 0ull) break;
                    int a = (int)s_ix[bpos];
                    float wscore = __uint_as_float((unsigned)(bk >> 32));
                    if (lane == 0) s_ix[bpos] = 0xFFFFu;
                    float4 wb = bb[a];
                    float war = (wb.z - wb.x) * (wb.w - wb.y);
                    bool sup = false;
                    if (lane < na) {
                        float xx1 = fmaxf(s_acc[lane][0], wb.x), yy1 = fmaxf(s_acc[lane][1], wb.y);
                        float xx2 = fminf(s_acc[lane][2], wb.z), yy2 = fminf(s_acc[lane][3], wb.w);
                        float iw = fmaxf(xx2 - xx1, 0.f), ih = fmaxf(yy2 - yy1, 0.f);
                        float inter = iw * ih;
                        float den = (s_acc[lane][4] + war) - inter;
                        sup = ((double)inter > (double)den * SUPC);
                    }
                    if (__ballot(sup) == 0ull) {
                        if (lane == 0) {
                            orow[na * 5 + 0] = wscore;
                            orow[na * 5 + 1] = wb.x; orow[na * 5 + 2] = wb.y;
                            orow[na * 5 + 3] = wb.z; orow[na * 5 + 4] = wb.w;
                            s_acc[na][0] = wb.x; s_acc[na][1] = wb.y;
                            s_acc[na][2] = wb.z; s_acc[na][3] = wb.w;
                            s_acc[na][4] = war;
                        }
                        na++;
                    }
                }
                if (lane == 0) s_ctrl[0] = na;
            }
            __syncthreads();
            hi = lo;
        }
    }

    __syncthreads();
    const int naF = s_ctrl[0];
    for (int z = naF * 5 + t; z < TOPK * 5; z += 256) orow[z] = 0.f;
}

// ============== round-1 fallback (only if ws too small for fast path) ==============
#define OTHREADS 1024
#define OCAP 10240
#define OJMAX 10

__global__ __launch_bounds__(OTHREADS) void nms_old_k(const float* __restrict__ conf,
                                                      const float* __restrict__ boxes,
                                                      float* __restrict__ out) {
#pragma clang fp contract(off)
    const int blk = blockIdx.x;
    const int b = blk / NC, c = blk - b * NC;
    const int t = threadIdx.x;
    const int lane = t & 63, wid = t >> 6;
    __shared__ float s_val[OCAP];
    __shared__ unsigned short s_idx[OCAP];
    __shared__ float s_ps[2][16];
    __shared__ int s_pa[2][16];
    __shared__ int s_n;
    if (t == 0) s_n = 0;
    __syncthreads();
    const float* cp = conf + ((size_t)b * NA) * NC + c;
    float v[NA / OTHREADS];
#pragma unroll
    for (int r = 0; r < NA / OTHREADS; ++r)
        v[r] = cp[(size_t)(r * OTHREADS + t) * NC];
#pragma unroll
    for (int r = 0; r < NA / OTHREADS; ++r) {
        int a = r * OTHREADS + t;
        bool alive = v[r] > 0.5f;
        unsigned long long m = __ballot(alive);
        int cnt = __popcll(m);
        int base = 0;
        if (lane == 0 && cnt) base = atomicAdd(&s_n, cnt);
        base = __shfl(base, 0);
        if (alive) {
            int p = base + __popcll(m & ((1ull << lane) - 1));
            if (p < OCAP) { s_val[p] = v[r]; s_idx[p] = (unsigned short)a; }
        }
    }
    __syncthreads();
    int n = s_n; if (n > OCAP) n = OCAP;
    const int jn = (n + OTHREADS - 1) / OTHREADS;
    const float4* bb = (const float4*)boxes + (size_t)b * NA;
    float sc[OJMAX]; float4 bx[OJMAX]; int ia[OJMAX];
#pragma unroll
    for (int j = 0; j < OJMAX; ++j) {
        sc[j] = NEGF; ia[j] = 0x7fffffff; bx[j] = make_float4(0.f, 0.f, 0.f, 0.f);
        int p = j * OTHREADS + t;
        if (p < n) { sc[j] = s_val[p]; ia[j] = (int)s_idx[p]; bx[j] = bb[ia[j]]; }
    }
    float* orow = out + (size_t)blk * (TOPK * 5);
    int k = 0;
    for (; k < TOPK; ++k) {
        float ms = NEGF; int ma = 0x7fffffff;
#pragma unroll
        for (int j = 0; j < OJMAX; ++j) {
            if (j < jn) {
                bool better = (sc[j] > ms) || (sc[j] == ms && ia[j] < ma);
                ms = better ? sc[j] : ms;
                ma = better ? ia[j] : ma;
            }
        }
#pragma unroll
        for (int off = 32; off; off >>= 1) {
            float os = __shfl_xor(ms, off);
            int oa = __shfl_xor(ma, off);
            if (os > ms || (os == ms && oa < ma)) { ms = os; ma = oa; }
        }
        int pb = k & 1;
        if (lane == 0) { s_ps[pb][wid] = ms; s_pa[pb][wid] = ma; }
        __syncthreads();
        float wsv = NEGF; int wa = 0x7fffffff;
#pragma unroll
        for (int w = 0; w < 16; ++w) {
            float os = s_ps[pb][w]; int oa = s_pa[pb][w];
            if (os > wsv || (os == wsv && oa < wa)) { wsv = os; wa = oa; }
        }
        if (!(wsv > NEGF)) break;
        float4 wb = bb[wa];
        float warea = (wb.z - wb.x) * (wb.w - wb.y);
        if (t == 0) {
            orow[k * 5 + 0] = wsv;
            orow[k * 5 + 1] = wb.x; orow[k * 5 + 2] = wb.y;
            orow[k * 5 + 3] = wb.z; orow[k * 5 + 4] = wb.w;
        }
#pragma unroll
        for (int j = 0; j < OJMAX; ++j) {
            if (j < jn) {
                float xx1 = fmaxf(wb.x, bx[j].x);
                float yy1 = fmaxf(wb.y, bx[j].y);
                float xx2 = fminf(wb.z, bx[j].z);
                float yy2 = fminf(wb.w, bx[j].w);
                float iw = fmaxf(xx2 - xx1, 0.f);
                float ih = fmaxf(yy2 - yy1, 0.f);
                float inter = iw * ih;
                float aj = (bx[j].z - bx[j].x) * (bx[j].w - bx[j].y);
                float denom = (warea + aj) - inter;
                bool supp = ((double)inter > (double)denom * SUPC) || (ia[j] == wa);
                if (supp) sc[j] = NEGF;
            }
        }
    }
    for (int z = k * 5 + t; z < TOPK * 5; z += OTHREADS) orow[z] = 0.f;
}

extern "C" void kernel_launch(void* const* d_in, const int* in_sizes, int n_in,
                              void* d_out, int out_size, void* d_ws, size_t ws_size,
                              hipStream_t stream) {
    const float* conf = (const float*)d_in[0];   // [B,A,C] f32
    const float* loc  = (const float*)d_in[1];   // [B,A,4] f32
    const float* anc  = (const float*)d_in[2];   // [A,4]   f32
    float* boxes = (float*)d_ws;

    decode_k<<<(NB * NA + 255) / 256, 256, 0, stream>>>(loc, anc, boxes);

    if (ws_size >= WS_FULL) {
        unsigned short* confT = (unsigned short*)((char*)d_ws + WS_CONFT_OFF);
        dim3 tg(NA / TSLAB, NB);                 // (64, 16)
        transq_k<<<tg, 256, 0, stream>>>(conf, confT);
        nmsB4_k<<<NB * NC, 256, 0, stream>>>(confT, conf, boxes, (float*)d_out);
    } else {
        nms_old_k<<<NB * NC, OTHREADS, 0, stream>>>(conf, boxes, (float*)d_out);
    }
}

// Round 8
// 210.592 us; speedup vs baseline: 2.0736x; 1.0976x over previous
//
#include <hip/hip_runtime.h>
#include <math.h>

#define NB 16
#define NA 16384
#define NC 81
#define TOPK 50
#define NBK 255                            // u8 buckets 0..254 (255=sentinel)
#define TRC 8960                           // >= n_max ~ 8192+6sigma: single tranche
#define NEGF (-__builtin_inff())
#define SUPC 0.5000000298023223876953125   // 0.5 + 2^-25 (exact in double)

typedef unsigned long long ull;

// ws layout: boxes [NB*NA*4 f32] @0 (4 MiB), confT8 [NB*NC*NA u8] @4 MiB (21.2 MB)
#define WS_CONFT_OFF  ((size_t)4194304)
#define WS_FULL  (WS_CONFT_OFF + (size_t)NB * NC * NA)       // 25,427,968

// ---------------- decode + clip (bit-verified rounds 1-7 — DO NOT TOUCH) ----------
__global__ __launch_bounds__(256) void decode_k(const float* __restrict__ loc,
                                                const float* __restrict__ anc,
                                                float* __restrict__ boxes) {
#pragma clang fp contract(off)
    int i = blockIdx.x * 256 + threadIdx.x;
    if (i >= NB * NA) return;
    int a = i & (NA - 1);
    float4 an = ((const float4*)anc)[a];
    float4 ld = ((const float4*)loc)[i];
    float cx = an.x + (ld.x * 0.1f) * an.z;
    float cy = an.y + (ld.y * 0.1f) * an.w;
    float w = an.z * (float)exp((double)(ld.z * 0.2f));
    float h = an.w * (float)exp((double)(ld.w * 0.2f));
    float x1 = cx - w * 0.5f;
    float y1 = cy - h * 0.5f;
    float x2 = x1 + w;
    float y2 = y1 + h;
    x1 = fminf(fmaxf(x1, 0.f), 1.f);
    y1 = fminf(fmaxf(y1, 0.f), 1.f);
    x2 = fminf(fmaxf(x2, 0.f), 1.f);
    y2 = fminf(fmaxf(y2, 0.f), 1.f);
    ((float4*)boxes)[i] = make_float4(x1, y1, x2, y2);
}

// score -> u8 code: 8-bit DESCENDING bucket for v in (0.5,1); 0xFF = not-candidate.
// desc 255 (lowest slice) merged into 254 — exact: resolve uses full f32 keys on
// complete buckets, so merging adjacent buckets never reorders accepted output.
__device__ __forceinline__ unsigned enc8(float v) {
    unsigned e = 0xFFu;
    if (v > 0.5f) {
        unsigned d = 255u - ((__float_as_uint(v) >> 15) & 0xFFu);
        e = (d > 254u) ? 254u : d;
    }
    return e;
}

// ---------------- transpose v4: conf f32 [B,A,C] -> confT8 u8 codes [B,C,A] ----------
// Block = (b, 512-anchor slab). Flat LDS store (contiguous uchar4/lane: free) +
// strided LDS read (4-way: 1.58x) — fixes v3's ~64-way LDS scatter-write conflicts.
// Global: 166 KB contiguous float4 read per block; 512 B u64 write runs per class.
#define TSLAB 512
__global__ __launch_bounds__(256) void transq_k(const float* __restrict__ conf,
                                                unsigned char* __restrict__ confT) {
    __shared__ unsigned char code[TSLAB * NC];     // flat [a*81+c], 41472 B
    const int b = blockIdx.y;
    const int slab = blockIdx.x;
    const float4* src = (const float4*)(conf + ((size_t)b * NA + (size_t)slab * TSLAB) * NC);
    const int t = threadIdx.x;
    for (int i = t; i < (TSLAB * NC) / 4; i += 256) {
        float4 v = src[i];
        unsigned wrd = enc8(v.x) | (enc8(v.y) << 8) | (enc8(v.z) << 16) | (enc8(v.w) << 24);
        *(unsigned*)&code[4 * i] = wrd;            // contiguous 4 B/lane: conflict-free
    }
    __syncthreads();
    const int lane = t & 63, wv = t >> 6;
    for (int c = wv; c < NC; c += 4) {             // 64 lanes x 8 B = 512 B run per class
        ull v = 0ull;
#pragma unroll
        for (int j = 0; j < 8; ++j)
            v |= (ull)code[(8 * lane + j) * NC + c] << (8 * j);
        *(ull*)(confT + ((size_t)b * NC + c) * NA + (size_t)slab * TSLAB + 8 * lane) = v;
    }
}

// ---------------- bucket-sorted lazy greedy NMS v5: u8 rows, single tranche ----------
__global__ __launch_bounds__(256, 6) void nmsB5_k(const unsigned char* __restrict__ confT,
                                                  const float* __restrict__ conf,
                                                  const float* __restrict__ boxes,
                                                  float* __restrict__ out) {
#pragma clang fp contract(off)
    const int blk = blockIdx.x;
    const int b = blk / NC, c = blk - b * NC;
    const int t = threadIdx.x;
    const int lane = t & 63, wv = t >> 6;

    __shared__ unsigned short s_ix[TRC];        // 17920 B
    __shared__ unsigned s_off[NBK + 1];         // bucket starts (desc score order)
    __shared__ unsigned s_aux[NBK];             // hist -> cursors
    __shared__ float s_acc[TOPK][5];            // accepted x1,y1,x2,y2,area
    __shared__ float4 s_cbox[256];              // per-round candidate boxes
    __shared__ unsigned long long s_kill[4];
    __shared__ int s_ctrl[16];
    // ctrl: 0=nacc 1=tmp 2..5=chunk starts 6=chunk end 7=bptr 8=maxbucket
    //       9=bigE0 10=bigE1 11=mode 12=trLo 13=trHi

    const uint4* row16 = (const uint4*)(confT + ((size_t)b * NC + c) * NA); // 16 codes/16B
    const float* cp = conf + ((size_t)b * NA) * NC + c;   // exact scores, L3-hot
    const float4* bb = (const float4*)boxes + (size_t)b * NA;
    float* orow = out + ((size_t)b * NC + c) * (TOPK * 5);

    // --- histogram over 255 buckets from u8 codes (16 KB row, 4 uint4/thread) ---
    if (t < NBK) s_aux[t] = 0u;
    if (t == 0) { s_ctrl[0] = 0; s_ctrl[8] = 0; s_ctrl[12] = 0; }
    __syncthreads();
#pragma unroll
    for (int r = 0; r < 4; ++r) {
        uint4 q = row16[t + 256 * r];
        unsigned wrds[4] = {q.x, q.y, q.z, q.w};
#pragma unroll
        for (int m = 0; m < 4; ++m)
#pragma unroll
            for (int k = 0; k < 4; ++k) {
                unsigned bk = (wrds[m] >> (8 * k)) & 0xFFu;
                if (bk != 0xFFu) atomicAdd(&s_aux[bk], 1u);
            }
    }
    __syncthreads();
    if (t < NBK) atomicMax(&s_ctrl[8], (int)s_aux[t]);
    // --- exclusive prefix -> s_off[0..255] (Hillis-Steele, 8 steps) ---
    if (t == 0) s_off[0] = 0u;
    if (t < NBK) s_off[t + 1] = s_aux[t];
    __syncthreads();
    for (int d = 1; d < 256; d <<= 1) {
        unsigned v0 = 0u;
        if (t < NBK) v0 = (1 + t - d >= 1) ? s_off[1 + t - d] : 0u;
        __syncthreads();
        if (t < NBK) s_off[1 + t] += v0;
        __syncthreads();
    }

    if (s_ctrl[8] <= TRC) {
        // =========================== fast path: tranche loop ===========================
        while (true) {
            if (t == 0) {
                int lo = s_ctrl[12];
                int hi = lo;
                while (hi < NBK && s_off[hi + 1] - s_off[lo] <= (unsigned)TRC) hi++;
                s_ctrl[13] = hi;
            }
            __syncthreads();
            const int trLo = s_ctrl[12], trHi = s_ctrl[13];
            const unsigned tbase = s_off[trLo], tend = s_off[trHi];
            if (tbase == tend) break;               // no candidates remain
            for (int i = trLo + t; i < trHi; i += 256) s_aux[i] = s_off[i] - tbase;
            __syncthreads();
            // --- scatter tranche's anchor indices (code row is L1/L2-hot, 16 KB) ---
#pragma unroll
            for (int r = 0; r < 4; ++r) {
                uint4 q = row16[t + 256 * r];
                unsigned wrds[4] = {q.x, q.y, q.z, q.w};
                int base_a = 16 * (t + 256 * r);
#pragma unroll
                for (int m = 0; m < 4; ++m)
#pragma unroll
                    for (int k = 0; k < 4; ++k) {
                        int bk = (int)((wrds[m] >> (8 * k)) & 0xFFu);
                        if (bk >= trLo && bk < trHi)     // 0xFF never passes (trHi<=255)
                            s_ix[atomicAdd(&s_aux[bk], 1u)] =
                                (unsigned short)(base_a + 4 * m + k);
                    }
            }
            if (t == 0) s_ctrl[7] = trLo;
            __syncthreads();

            // --- rounds: 4 bucket-aligned chunks of <=64, parallel test + serial resolve ---
            while (true) {
                if (t == 0) {
                    int bp = s_ctrl[7];
                    int mode;
                    if (bp >= trHi || s_off[bp] >= tend) {
                        mode = 2;
                    } else {
                        unsigned pos = s_off[bp] - tbase;
                        int bpl = bp;
                        unsigned q = pos;
                        for (int w = 0; w < 4; ++w) {
                            s_ctrl[2 + w] = (int)q;
                            while (bpl < trHi && (s_off[bpl + 1] - tbase - q) <= 64u) bpl++;
                            q = (bpl < trHi) ? s_off[bpl] - tbase : tend - tbase;
                        }
                        s_ctrl[6] = (int)q;
                        s_ctrl[7] = bpl;
                        mode = 0;
                        if (q == pos) {            // first bucket > 64 entries (rare)
                            mode = 1;
                            s_ctrl[9] = (int)pos;
                            s_ctrl[10] = (int)(s_off[bp + 1] - tbase);
                            s_ctrl[7] = bp + 1;
                        }
                    }
                    s_ctrl[11] = mode;
                }
                __syncthreads();
                const int mode = s_ctrl[11];
                if (mode == 2) break;
                const int nacc0 = s_ctrl[0];

                if (mode == 0) {
                    const unsigned q0 = (unsigned)s_ctrl[2 + wv];
                    const unsigned q1 = (unsigned)s_ctrl[3 + wv];
                    const int mw = (int)(q1 - q0);
                    const bool valid = lane < mw;
                    int ii = (int)q0 + lane; if (ii > TRC - 1) ii = TRC - 1;
                    int a = valid ? (int)s_ix[ii] : 0;
                    float4 bxv = bb[a];
                    if (!valid) bxv = make_float4(0.f, 0.f, 0.f, 0.f);
                    s_cbox[wv * 64 + lane] = bxv;
                    float mar = (bxv.z - bxv.x) * (bxv.w - bxv.y);
                    bool kill = !valid;
                    for (int j = 0; j < nacc0; ++j) {
                        float xx1 = fmaxf(s_acc[j][0], bxv.x), yy1 = fmaxf(s_acc[j][1], bxv.y);
                        float xx2 = fminf(s_acc[j][2], bxv.z), yy2 = fminf(s_acc[j][3], bxv.w);
                        float iw = fmaxf(xx2 - xx1, 0.f), ih = fmaxf(yy2 - yy1, 0.f);
                        float inter = iw * ih;
                        float den = (s_acc[j][4] + mar) - inter;
                        if ((double)inter > (double)den * SUPC) kill = true;
                    }
                    unsigned long long km = __ballot(kill);
                    if (lane == 0) s_kill[wv] = km;
                    __syncthreads();

                    if (wv == 0) {
                        int na = nacc0;
                        for (int cc = 0; cc < 4 && na < TOPK; ++cc) {
                            const unsigned e0 = (unsigned)s_ctrl[2 + cc];
                            const unsigned e1 = (unsigned)s_ctrl[3 + cc];
                            const int mc = (int)(e1 - e0);
                            if (mc <= 0) continue;
                            unsigned long long alive = ~s_kill[cc];
                            if (mc < 64) alive &= (1ull << mc) - 1ull;
                            int jj = (int)e0 + lane; if (jj > TRC - 1) jj = TRC - 1;
                            int aj = (lane < mc) ? (int)s_ix[jj] : 0;
                            float myscore = cp[(size_t)aj * NC];       // exact f32, L3-hot
                            float4 mybx = s_cbox[cc * 64 + lane];
                            float mar2 = (mybx.z - mybx.x) * (mybx.w - mybx.y);
                            for (int j = nacc0; j < na && alive; ++j) {
                                float xx1 = fmaxf(s_acc[j][0], mybx.x), yy1 = fmaxf(s_acc[j][1], mybx.y);
                                float xx2 = fminf(s_acc[j][2], mybx.z), yy2 = fminf(s_acc[j][3], mybx.w);
                                float iw = fmaxf(xx2 - xx1, 0.f), ih = fmaxf(yy2 - yy1, 0.f);
                                float inter = iw * ih;
                                float den = (s_acc[j][4] + mar2) - inter;
                                bool sup = ((double)inter > (double)den * SUPC);
                                alive &= ~__ballot(sup);
                            }
                            unsigned long long mykey =
                                ((unsigned long long)__float_as_uint(myscore) << 32) |
                                (unsigned)(16383 - aj);
                            while (alive && na < TOPK) {
                                unsigned long long kk = ((alive >> lane) & 1ull) ? mykey : 0ull;
                                int src = lane;
                                for (int off = 32; off; off >>= 1) {
                                    unsigned long long ok = __shfl_xor(kk, off);
                                    int osrc = __shfl_xor(src, off);
                                    if (ok > kk) { kk = ok; src = osrc; }
                                }
                                float4 wb = s_cbox[cc * 64 + src];
                                float wscore = __shfl(myscore, src);
                                float war = (wb.z - wb.x) * (wb.w - wb.y);
                                if (lane == 0) {
                                    orow[na * 5 + 0] = wscore;
                                    orow[na * 5 + 1] = wb.x; orow[na * 5 + 2] = wb.y;
                                    orow[na * 5 + 3] = wb.z; orow[na * 5 + 4] = wb.w;
                                    s_acc[na][0] = wb.x; s_acc[na][1] = wb.y;
                                    s_acc[na][2] = wb.z; s_acc[na][3] = wb.w;
                                    s_acc[na][4] = war;
                                }
                                na++;
                                alive &= ~(1ull << src);
                                if (alive) {
                                    float xx1 = fmaxf(wb.x, mybx.x), yy1 = fmaxf(wb.y, mybx.y);
                                    float xx2 = fminf(wb.z, mybx.z), yy2 = fminf(wb.w, mybx.w);
                                    float iw = fmaxf(xx2 - xx1, 0.f), ih = fmaxf(yy2 - yy1, 0.f);
                                    float inter = iw * ih;
                                    float den = (war + mar2) - inter;
                                    bool sup = ((double)inter > (double)den * SUPC);
                                    alive &= ~__ballot(sup);
                                }
                            }
                        }
                        if (lane == 0) s_ctrl[0] = na;
                    }
                    __syncthreads();
                } else {
                    // big-bucket (>64 in one bucket, <=TRC): wave-0 extraction
                    const int e0 = s_ctrl[9], e1 = s_ctrl[10];
                    if (wv == 0) {
                        int na = s_ctrl[0];
                        while (na < TOPK) {
                            unsigned long long bk = 0ull; int bpos = 0;
                            for (int i = e0 + lane; i < e1; i += 64) {
                                int av = (int)s_ix[i];
                                if (av != 0xFFFF) {
                                    float v = cp[(size_t)av * NC];
                                    unsigned long long k =
                                        ((unsigned long long)__float_as_uint(v) << 32) |
                                        (unsigned)(16383 - av);
                                    if (k > bk) { bk = k; bpos = i; }
                                }
                            }
                            for (int off = 32; off; off >>= 1) {
                                unsigned long long ok = __shfl_xor(bk, off);
                                int op = __shfl_xor(bpos, off);
                                if (ok > bk) { bk = ok; bpos = op; }
                            }
                            if (bk == 0ull) break;
                            int a = (int)s_ix[bpos];
                            float wscore = __uint_as_float((unsigned)(bk >> 32));
                            if (lane == 0) s_ix[bpos] = 0xFFFFu;     // consume
                            float4 wb = bb[a];
                            float war = (wb.z - wb.x) * (wb.w - wb.y);
                            bool sup = false;
                            if (lane < na) {
                                float xx1 = fmaxf(s_acc[lane][0], wb.x), yy1 = fmaxf(s_acc[lane][1], wb.y);
                                float xx2 = fminf(s_acc[lane][2], wb.z), yy2 = fminf(s_acc[lane][3], wb.w);
                                float iw = fmaxf(xx2 - xx1, 0.f), ih = fmaxf(yy2 - yy1, 0.f);
                                float inter = iw * ih;
                                float den = (s_acc[lane][4] + war) - inter;
                                sup = ((double)inter > (double)den * SUPC);
                            }
                            if (__ballot(sup) == 0ull) {
                                if (lane == 0) {
                                    orow[na * 5 + 0] = wscore;
                                    orow[na * 5 + 1] = wb.x; orow[na * 5 + 2] = wb.y;
                                    orow[na * 5 + 3] = wb.z; orow[na * 5 + 4] = wb.w;
                                    s_acc[na][0] = wb.x; s_acc[na][1] = wb.y;
                                    s_acc[na][2] = wb.z; s_acc[na][3] = wb.w;
                                    s_acc[na][4] = war;
                                }
                                na++;
                            }
                        }
                        if (lane == 0) s_ctrl[0] = na;
                    }
                    __syncthreads();
                }
                if (s_ctrl[0] >= TOPK) break;
            }
            // --- tranche done ---
            if (s_ctrl[0] >= TOPK || trHi >= NBK) break;
            if (t == 0) s_ctrl[12] = trHi;
            __syncthreads();
        }
    } else {
        // ===== exact windowed path (single bucket > TRC; P~0): strided conf scan =====
        float hi = 1.0f, delta = 0.02f;
        while (true) {
            if (s_ctrl[0] >= TOPK || hi <= 0.5f) break;
            float lo = fmaxf(hi - delta, 0.5f);
            if (t == 0) s_ctrl[1] = 0;
            __syncthreads();
            for (int a = t; a < NA; a += 256) {
                float v = cp[(size_t)a * NC];
                if (v > lo && v <= hi) {
                    int p = atomicAdd(&s_ctrl[1], 1);
                    if (p < TRC) s_ix[p] = (unsigned short)a;
                }
            }
            __syncthreads();
            int m = s_ctrl[1];
            if (m > TRC) { delta *= 0.5f; continue; }
            if (wv == 0) {
                int na = s_ctrl[0];
                while (na < TOPK) {
                    unsigned long long bk = 0ull; int bpos = 0;
                    for (int i = lane; i < m; i += 64) {
                        int av = (int)s_ix[i];
                        if (av != 0xFFFF) {
                            float v = cp[(size_t)av * NC];
                            unsigned long long k =
                                ((unsigned long long)__float_as_uint(v) << 32) |
                                (unsigned)(16383 - av);
                            if (k > bk) { bk = k; bpos = i; }
                        }
                    }
                    for (int off = 32; off; off >>= 1) {
                        unsigned long long ok = __shfl_xor(bk, off);
                        int op = __shfl_xor(bpos, off);
                        if (ok > bk) { bk = ok; bpos = op; }
                    }
                    if (bk == 0ull) break;
                    int a = (int)s_ix[bpos];
                    float wscore = __uint_as_float((unsigned)(bk >> 32));
                    if (lane == 0) s_ix[bpos] = 0xFFFFu;
                    float4 wb = bb[a];
                    float war = (wb.z - wb.x) * (wb.w - wb.y);
                    bool sup = false;
                    if (lane < na) {
                        float xx1 = fmaxf(s_acc[lane][0], wb.x), yy1 = fmaxf(s_acc[lane][1], wb.y);
                        float xx2 = fminf(s_acc[lane][2], wb.z), yy2 = fminf(s_acc[lane][3], wb.w);
                        float iw = fmaxf(xx2 - xx1, 0.f), ih = fmaxf(yy2 - yy1, 0.f);
                        float inter = iw * ih;
                        float den = (s_acc[lane][4] + war) - inter;
                        sup = ((double)inter > (double)den * SUPC);
                    }
                    if (__ballot(sup) == 0ull) {
                        if (lane == 0) {
                            orow[na * 5 + 0] = wscore;
                            orow[na * 5 + 1] = wb.x; orow[na * 5 + 2] = wb.y;
                            orow[na * 5 + 3] = wb.z; orow[na * 5 + 4] = wb.w;
                            s_acc[na][0] = wb.x; s_acc[na][1] = wb.y;
                            s_acc[na][2] = wb.z; s_acc[na][3] = wb.w;
                            s_acc[na][4] = war;
                        }
                        na++;
                    }
                }
                if (lane == 0) s_ctrl[0] = na;
            }
            __syncthreads();
            hi = lo;
        }
    }

    __syncthreads();
    const int naF = s_ctrl[0];
    for (int z = naF * 5 + t; z < TOPK * 5; z += 256) orow[z] = 0.f;
}

// ============== round-1 fallback (only if ws too small for fast path) ==============
#define OTHREADS 1024
#define OCAP 10240
#define OJMAX 10

__global__ __launch_bounds__(OTHREADS) void nms_old_k(const float* __restrict__ conf,
                                                      const float* __restrict__ boxes,
                                                      float* __restrict__ out) {
#pragma clang fp contract(off)
    const int blk = blockIdx.x;
    const int b = blk / NC, c = blk - b * NC;
    const int t = threadIdx.x;
    const int lane = t & 63, wid = t >> 6;
    __shared__ float s_val[OCAP];
    __shared__ unsigned short s_idx[OCAP];
    __shared__ float s_ps[2][16];
    __shared__ int s_pa[2][16];
    __shared__ int s_n;
    if (t == 0) s_n = 0;
    __syncthreads();
    const float* cp = conf + ((size_t)b * NA) * NC + c;
    float v[NA / OTHREADS];
#pragma unroll
    for (int r = 0; r < NA / OTHREADS; ++r)
        v[r] = cp[(size_t)(r * OTHREADS + t) * NC];
#pragma unroll
    for (int r = 0; r < NA / OTHREADS; ++r) {
        int a = r * OTHREADS + t;
        bool alive = v[r] > 0.5f;
        unsigned long long m = __ballot(alive);
        int cnt = __popcll(m);
        int base = 0;
        if (lane == 0 && cnt) base = atomicAdd(&s_n, cnt);
        base = __shfl(base, 0);
        if (alive) {
            int p = base + __popcll(m & ((1ull << lane) - 1));
            if (p < OCAP) { s_val[p] = v[r]; s_idx[p] = (unsigned short)a; }
        }
    }
    __syncthreads();
    int n = s_n; if (n > OCAP) n = OCAP;
    const int jn = (n + OTHREADS - 1) / OTHREADS;
    const float4* bb = (const float4*)boxes + (size_t)b * NA;
    float sc[OJMAX]; float4 bx[OJMAX]; int ia[OJMAX];
#pragma unroll
    for (int j = 0; j < OJMAX; ++j) {
        sc[j] = NEGF; ia[j] = 0x7fffffff; bx[j] = make_float4(0.f, 0.f, 0.f, 0.f);
        int p = j * OTHREADS + t;
        if (p < n) { sc[j] = s_val[p]; ia[j] = (int)s_idx[p]; bx[j] = bb[ia[j]]; }
    }
    float* orow = out + (size_t)blk * (TOPK * 5);
    int k = 0;
    for (; k < TOPK; ++k) {
        float ms = NEGF; int ma = 0x7fffffff;
#pragma unroll
        for (int j = 0; j < OJMAX; ++j) {
            if (j < jn) {
                bool better = (sc[j] > ms) || (sc[j] == ms && ia[j] < ma);
                ms = better ? sc[j] : ms;
                ma = better ? ia[j] : ma;
            }
        }
#pragma unroll
        for (int off = 32; off; off >>= 1) {
            float os = __shfl_xor(ms, off);
            int oa = __shfl_xor(ma, off);
            if (os > ms || (os == ms && oa < ma)) { ms = os; ma = oa; }
        }
        int pb = k & 1;
        if (lane == 0) { s_ps[pb][wid] = ms; s_pa[pb][wid] = ma; }
        __syncthreads();
        float wsv = NEGF; int wa = 0x7fffffff;
#pragma unroll
        for (int w = 0; w < 16; ++w) {
            float os = s_ps[pb][w]; int oa = s_pa[pb][w];
            if (os > wsv || (os == wsv && oa < wa)) { wsv = os; wa = oa; }
        }
        if (!(wsv > NEGF)) break;
        float4 wb = bb[wa];
        float warea = (wb.z - wb.x) * (wb.w - wb.y);
        if (t == 0) {
            orow[k * 5 + 0] = wsv;
            orow[k * 5 + 1] = wb.x; orow[k * 5 + 2] = wb.y;
            orow[k * 5 + 3] = wb.z; orow[k * 5 + 4] = wb.w;
        }
#pragma unroll
        for (int j = 0; j < OJMAX; ++j) {
            if (j < jn) {
                float xx1 = fmaxf(wb.x, bx[j].x);
                float yy1 = fmaxf(wb.y, bx[j].y);
                float xx2 = fminf(wb.z, bx[j].z);
                float yy2 = fminf(wb.w, bx[j].w);
                float iw = fmaxf(xx2 - xx1, 0.f);
                float ih = fmaxf(yy2 - yy1, 0.f);
                float inter = iw * ih;
                float aj = (bx[j].z - bx[j].x) * (bx[j].w - bx[j].y);
                float denom = (warea + aj) - inter;
                bool supp = ((double)inter > (double)denom * SUPC) || (ia[j] == wa);
                if (supp) sc[j] = NEGF;
            }
        }
    }
    for (int z = k * 5 + t; z < TOPK * 5; z += OTHREADS) orow[z] = 0.f;
}

extern "C" void kernel_launch(void* const* d_in, const int* in_sizes, int n_in,
                              void* d_out, int out_size, void* d_ws, size_t ws_size,
                              hipStream_t stream) {
    const float* conf = (const float*)d_in[0];   // [B,A,C] f32
    const float* loc  = (const float*)d_in[1];   // [B,A,4] f32
    const float* anc  = (const float*)d_in[2];   // [A,4]   f32
    float* boxes = (float*)d_ws;

    decode_k<<<(NB * NA + 255) / 256, 256, 0, stream>>>(loc, anc, boxes);

    if (ws_size >= WS_FULL) {
        unsigned char* confT = (unsigned char*)((char*)d_ws + WS_CONFT_OFF);
        dim3 tg(NA / TSLAB, NB);                 // (32, 16)
        transq_k<<<tg, 256, 0, stream>>>(conf, confT);
        nmsB5_k<<<NB * NC, 256, 0, stream>>>(confT, conf, boxes, (float*)d_out);
    } else {
        nms_old_k<<<NB * NC, OTHREADS, 0, stream>>>(conf, boxes, (float*)d_out);
    }
}

// Round 9
// 207.642 us; speedup vs baseline: 2.1031x; 1.0142x over previous
//
#include <hip/hip_runtime.h>
#include <math.h>

#define NB 16
#define NA 16384
#define NC 81
#define TOPK 50
#define NBK 255                            // u8 buckets 0..254 (255=sentinel)
#define TRC 8960                           // >= n_max ~ 8192+6sigma: single tranche
#define NEGF (-__builtin_inff())
#define SUPC 0.5000000298023223876953125   // 0.5 + 2^-25 (exact in double)

typedef unsigned long long ull;

// ws layout: boxes [NB*NA*4 f32] @0 (4 MiB), confT8 [NB*NC*NA u8] @4 MiB (21.2 MB)
#define WS_CONFT_OFF  ((size_t)4194304)
#define WS_FULL  (WS_CONFT_OFF + (size_t)NB * NC * NA)       // 25,427,968

// exact f32 form of: round_f32(inter/den) > 0.5  (== inter > den*(0.5+2^-25))
// Proof: boundary cases have IoU in [0.25,1] => inter in [den/4,den] => Sterbenz:
// fmaf(den,-0.5f,inter) is EXACT; den*2^-25 is an exponent shift (exact). Away from
// that range the two sides differ by >= den/4 >> ulp — rounding cannot flip the sign.
__device__ __forceinline__ bool iou_gt_half(float inter, float den) {
    return fmaf(den, -0.5f, inter) > den * 0x1p-25f;
}

// score -> u8 code: 8-bit DESCENDING bucket for v in (0.5,1); 0xFF = not-candidate.
// desc 255 merged into 254 — exact: resolve uses full f32 keys on complete buckets.
__device__ __forceinline__ unsigned enc8(float v) {
    unsigned e = 0xFFu;
    if (v > 0.5f) {
        unsigned d = 255u - ((__float_as_uint(v) >> 15) & 0xFFu);
        e = (d > 254u) ? 254u : d;
    }
    return e;
}

// ---------------- decode + clip (bit-verified rounds 1-8 — DO NOT TOUCH) ----------
__device__ __forceinline__ void decode_body(int i, const float* __restrict__ loc,
                                            const float* __restrict__ anc,
                                            float* __restrict__ boxes) {
#pragma clang fp contract(off)
    int a = i & (NA - 1);
    float4 an = ((const float4*)anc)[a];
    float4 ld = ((const float4*)loc)[i];
    float cx = an.x + (ld.x * 0.1f) * an.z;
    float cy = an.y + (ld.y * 0.1f) * an.w;
    float w = an.z * (float)exp((double)(ld.z * 0.2f));
    float h = an.w * (float)exp((double)(ld.w * 0.2f));
    float x1 = cx - w * 0.5f;
    float y1 = cy - h * 0.5f;
    float x2 = x1 + w;
    float y2 = y1 + h;
    x1 = fminf(fmaxf(x1, 0.f), 1.f);
    y1 = fminf(fmaxf(y1, 0.f), 1.f);
    x2 = fminf(fmaxf(x2, 0.f), 1.f);
    y2 = fminf(fmaxf(y2, 0.f), 1.f);
    ((float4*)boxes)[i] = make_float4(x1, y1, x2, y2);
}

__global__ __launch_bounds__(256) void decode_k(const float* __restrict__ loc,
                                                const float* __restrict__ anc,
                                                float* __restrict__ boxes) {
    int i = blockIdx.x * 256 + threadIdx.x;
    if (i < NB * NA) decode_body(i, loc, anc, boxes);
}

// ---------------- fused prep: z=0 -> u8-code transpose slab, z=1 -> decode slice -----
#define TSLAB 256
__global__ __launch_bounds__(256) void prep_k(const float* __restrict__ conf,
                                              const float* __restrict__ loc,
                                              const float* __restrict__ anc,
                                              float* __restrict__ boxes,
                                              unsigned char* __restrict__ confT) {
    __shared__ unsigned char code[TSLAB * NC];     // 20736 B (z=1 blocks ignore it)
    const int t = threadIdx.x;
    if (blockIdx.z == 1) {
        int i = (blockIdx.x + 64 * blockIdx.y) * 256 + t;   // 64*16 blocks = NB*NA/256
        if (i < NB * NA) decode_body(i, loc, anc, boxes);
        return;
    }
    // --- transpose: conf f32 [B,A,C] -> confT8 u8 codes [B,C,A] ---
    const int b = blockIdx.y, slab = blockIdx.x;
    const float4* src = (const float4*)(conf + ((size_t)b * NA + (size_t)slab * TSLAB) * NC);
    for (int i = t; i < (TSLAB * NC) / 4; i += 256) {
        float4 v = src[i];
        unsigned wrd = enc8(v.x) | (enc8(v.y) << 8) | (enc8(v.z) << 16) | (enc8(v.w) << 24);
        *(unsigned*)&code[4 * i] = wrd;            // contiguous 4 B/lane: conflict-free
    }
    __syncthreads();
    const int lane = t & 63, wv = t >> 6;
    for (int c = wv; c < NC; c += 4) {             // 64 lanes x 4 B = 256 B run per class
        unsigned v = 0u;
#pragma unroll
        for (int j = 0; j < 4; ++j)
            v |= (unsigned)code[(4 * lane + j) * NC + c] << (8 * j);
        *(unsigned*)(confT + ((size_t)b * NC + c) * NA + (size_t)slab * TSLAB + 4 * lane) = v;
    }
}

// ---------------- bucket-sorted lazy greedy NMS v6: float4 acc + f32-exact IoU -------
__global__ __launch_bounds__(256, 6) void nmsB6_k(const unsigned char* __restrict__ confT,
                                                  const float* __restrict__ conf,
                                                  const float* __restrict__ boxes,
                                                  float* __restrict__ out) {
#pragma clang fp contract(off)
    const int blk = blockIdx.x;
    const int b = blk / NC, c = blk - b * NC;
    const int t = threadIdx.x;
    const int lane = t & 63, wv = t >> 6;

    __shared__ unsigned short s_ix[TRC];        // 17920 B
    __shared__ unsigned s_off[NBK + 1];         // bucket starts (desc score order)
    __shared__ unsigned s_aux[NBK];             // hist -> cursors
    __shared__ float4 s_abox[TOPK];             // accepted boxes (b128 broadcast reads)
    __shared__ float s_aarea[TOPK];             // accepted areas
    __shared__ float4 s_cbox[256];              // per-round candidate boxes
    __shared__ unsigned long long s_kill[4];
    __shared__ int s_ctrl[16];
    // ctrl: 0=nacc 1=tmp 2..5=chunk starts 6=chunk end 7=bptr 8=maxbucket
    //       9=bigE0 10=bigE1 11=mode 12=trLo 13=trHi

    const uint4* row16 = (const uint4*)(confT + ((size_t)b * NC + c) * NA); // 16 codes/16B
    const float* cp = conf + ((size_t)b * NA) * NC + c;   // exact scores, L3-hot
    const float4* bb = (const float4*)boxes + (size_t)b * NA;
    float* orow = out + ((size_t)b * NC + c) * (TOPK * 5);

    // --- histogram over 255 buckets from u8 codes (16 KB row, 4 uint4/thread) ---
    if (t < NBK) s_aux[t] = 0u;
    if (t == 0) { s_ctrl[0] = 0; s_ctrl[8] = 0; s_ctrl[12] = 0; }
    __syncthreads();
#pragma unroll
    for (int r = 0; r < 4; ++r) {
        uint4 q = row16[t + 256 * r];
        unsigned wrds[4] = {q.x, q.y, q.z, q.w};
#pragma unroll
        for (int m = 0; m < 4; ++m)
#pragma unroll
            for (int k = 0; k < 4; ++k) {
                unsigned bk = (wrds[m] >> (8 * k)) & 0xFFu;
                if (bk != 0xFFu) atomicAdd(&s_aux[bk], 1u);
            }
    }
    __syncthreads();
    if (t < NBK) atomicMax(&s_ctrl[8], (int)s_aux[t]);
    // --- exclusive prefix -> s_off[0..255] (Hillis-Steele, 8 steps) ---
    if (t == 0) s_off[0] = 0u;
    if (t < NBK) s_off[t + 1] = s_aux[t];
    __syncthreads();
    for (int d = 1; d < 256; d <<= 1) {
        unsigned v0 = 0u;
        if (t < NBK) v0 = (1 + t - d >= 1) ? s_off[1 + t - d] : 0u;
        __syncthreads();
        if (t < NBK) s_off[1 + t] += v0;
        __syncthreads();
    }

    if (s_ctrl[8] <= TRC) {
        // =========================== fast path: tranche loop ===========================
        while (true) {
            if (t == 0) {
                int lo = s_ctrl[12];
                int hi = lo;
                while (hi < NBK && s_off[hi + 1] - s_off[lo] <= (unsigned)TRC) hi++;
                s_ctrl[13] = hi;
            }
            __syncthreads();
            const int trLo = s_ctrl[12], trHi = s_ctrl[13];
            const unsigned tbase = s_off[trLo], tend = s_off[trHi];
            if (tbase == tend) break;               // no candidates remain
            for (int i = trLo + t; i < trHi; i += 256) s_aux[i] = s_off[i] - tbase;
            __syncthreads();
            // --- scatter tranche's anchor indices (code row is L1/L2-hot, 16 KB) ---
#pragma unroll
            for (int r = 0; r < 4; ++r) {
                uint4 q = row16[t + 256 * r];
                unsigned wrds[4] = {q.x, q.y, q.z, q.w};
                int base_a = 16 * (t + 256 * r);
#pragma unroll
                for (int m = 0; m < 4; ++m)
#pragma unroll
                    for (int k = 0; k < 4; ++k) {
                        int bk = (int)((wrds[m] >> (8 * k)) & 0xFFu);
                        if (bk >= trLo && bk < trHi)     // 0xFF never passes (trHi<=255)
                            s_ix[atomicAdd(&s_aux[bk], 1u)] =
                                (unsigned short)(base_a + 4 * m + k);
                    }
            }
            if (t == 0) s_ctrl[7] = trLo;
            __syncthreads();

            // --- rounds: 4 bucket-aligned chunks of <=64, parallel test + serial resolve ---
            while (true) {
                if (t == 0) {
                    int bp = s_ctrl[7];
                    int mode;
                    if (bp >= trHi || s_off[bp] >= tend) {
                        mode = 2;
                    } else {
                        unsigned pos = s_off[bp] - tbase;
                        int bpl = bp;
                        unsigned q = pos;
                        for (int w = 0; w < 4; ++w) {
                            s_ctrl[2 + w] = (int)q;
                            while (bpl < trHi && (s_off[bpl + 1] - tbase - q) <= 64u) bpl++;
                            q = (bpl < trHi) ? s_off[bpl] - tbase : tend - tbase;
                        }
                        s_ctrl[6] = (int)q;
                        s_ctrl[7] = bpl;
                        mode = 0;
                        if (q == pos) {            // first bucket > 64 entries (rare)
                            mode = 1;
                            s_ctrl[9] = (int)pos;
                            s_ctrl[10] = (int)(s_off[bp + 1] - tbase);
                            s_ctrl[7] = bp + 1;
                        }
                    }
                    s_ctrl[11] = mode;
                }
                __syncthreads();
                const int mode = s_ctrl[11];
                if (mode == 2) break;
                const int nacc0 = s_ctrl[0];

                if (mode == 0) {
                    const unsigned q0 = (unsigned)s_ctrl[2 + wv];
                    const unsigned q1 = (unsigned)s_ctrl[3 + wv];
                    const int mw = (int)(q1 - q0);
                    const bool valid = lane < mw;
                    int ii = (int)q0 + lane; if (ii > TRC - 1) ii = TRC - 1;
                    int a = valid ? (int)s_ix[ii] : 0;
                    float4 bxv = bb[a];
                    if (!valid) bxv = make_float4(0.f, 0.f, 0.f, 0.f);
                    s_cbox[wv * 64 + lane] = bxv;
                    float mar = (bxv.z - bxv.x) * (bxv.w - bxv.y);
                    bool kill = !valid;
                    for (int j = 0; j < nacc0; ++j) {
                        float4 ab = s_abox[j];
                        float aa = s_aarea[j];
                        float xx1 = fmaxf(ab.x, bxv.x), yy1 = fmaxf(ab.y, bxv.y);
                        float xx2 = fminf(ab.z, bxv.z), yy2 = fminf(ab.w, bxv.w);
                        float iw = fmaxf(xx2 - xx1, 0.f), ih = fmaxf(yy2 - yy1, 0.f);
                        float inter = iw * ih;
                        float den = (aa + mar) - inter;
                        if (iou_gt_half(inter, den)) kill = true;
                    }
                    unsigned long long km = __ballot(kill);
                    if (lane == 0) s_kill[wv] = km;
                    __syncthreads();

                    if (wv == 0) {
                        int na = nacc0;
                        for (int cc = 0; cc < 4 && na < TOPK; ++cc) {
                            const unsigned e0 = (unsigned)s_ctrl[2 + cc];
                            const unsigned e1 = (unsigned)s_ctrl[3 + cc];
                            const int mc = (int)(e1 - e0);
                            if (mc <= 0) continue;
                            unsigned long long alive = ~s_kill[cc];
                            if (mc < 64) alive &= (1ull << mc) - 1ull;
                            int jj = (int)e0 + lane; if (jj > TRC - 1) jj = TRC - 1;
                            int aj = (lane < mc) ? (int)s_ix[jj] : 0;
                            float myscore = cp[(size_t)aj * NC];       // exact f32, L3-hot
                            float4 mybx = s_cbox[cc * 64 + lane];
                            float mar2 = (mybx.z - mybx.x) * (mybx.w - mybx.y);
                            for (int j = nacc0; j < na && alive; ++j) {
                                float4 ab = s_abox[j];
                                float aa = s_aarea[j];
                                float xx1 = fmaxf(ab.x, mybx.x), yy1 = fmaxf(ab.y, mybx.y);
                                float xx2 = fminf(ab.z, mybx.z), yy2 = fminf(ab.w, mybx.w);
                                float iw = fmaxf(xx2 - xx1, 0.f), ih = fmaxf(yy2 - yy1, 0.f);
                                float inter = iw * ih;
                                float den = (aa + mar2) - inter;
                                bool sup = iou_gt_half(inter, den);
                                alive &= ~__ballot(sup);
                            }
                            unsigned long long mykey =
                                ((unsigned long long)__float_as_uint(myscore) << 32) |
                                (unsigned)(16383 - aj);
                            while (alive && na < TOPK) {
                                unsigned long long kk = ((alive >> lane) & 1ull) ? mykey : 0ull;
                                int src = lane;
                                for (int off = 32; off; off >>= 1) {
                                    unsigned long long ok = __shfl_xor(kk, off);
                                    int osrc = __shfl_xor(src, off);
                                    if (ok > kk) { kk = ok; src = osrc; }
                                }
                                float4 wb = s_cbox[cc * 64 + src];
                                float wscore = __shfl(myscore, src);
                                float war = (wb.z - wb.x) * (wb.w - wb.y);
                                if (lane == 0) {
                                    orow[na * 5 + 0] = wscore;
                                    orow[na * 5 + 1] = wb.x; orow[na * 5 + 2] = wb.y;
                                    orow[na * 5 + 3] = wb.z; orow[na * 5 + 4] = wb.w;
                                    s_abox[na] = wb;
                                    s_aarea[na] = war;
                                }
                                na++;
                                alive &= ~(1ull << src);
                                if (alive) {
                                    float xx1 = fmaxf(wb.x, mybx.x), yy1 = fmaxf(wb.y, mybx.y);
                                    float xx2 = fminf(wb.z, mybx.z), yy2 = fminf(wb.w, mybx.w);
                                    float iw = fmaxf(xx2 - xx1, 0.f), ih = fmaxf(yy2 - yy1, 0.f);
                                    float inter = iw * ih;
                                    float den = (war + mar2) - inter;
                                    bool sup = iou_gt_half(inter, den);
                                    alive &= ~__ballot(sup);
                                }
                            }
                        }
                        if (lane == 0) s_ctrl[0] = na;
                    }
                    __syncthreads();
                } else {
                    // big-bucket (>64 in one bucket, <=TRC): wave-0 extraction
                    const int e0 = s_ctrl[9], e1 = s_ctrl[10];
                    if (wv == 0) {
                        int na = s_ctrl[0];
                        while (na < TOPK) {
                            unsigned long long bk = 0ull; int bpos = 0;
                            for (int i = e0 + lane; i < e1; i += 64) {
                                int av = (int)s_ix[i];
                                if (av != 0xFFFF) {
                                    float v = cp[(size_t)av * NC];
                                    unsigned long long k =
                                        ((unsigned long long)__float_as_uint(v) << 32) |
                                        (unsigned)(16383 - av);
                                    if (k > bk) { bk = k; bpos = i; }
                                }
                            }
                            for (int off = 32; off; off >>= 1) {
                                unsigned long long ok = __shfl_xor(bk, off);
                                int op = __shfl_xor(bpos, off);
                                if (ok > bk) { bk = ok; bpos = op; }
                            }
                            if (bk == 0ull) break;
                            int a = (int)s_ix[bpos];
                            float wscore = __uint_as_float((unsigned)(bk >> 32));
                            if (lane == 0) s_ix[bpos] = 0xFFFFu;     // consume
                            float4 wb = bb[a];
                            float war = (wb.z - wb.x) * (wb.w - wb.y);
                            bool sup = false;
                            if (lane < na) {
                                float4 ab = s_abox[lane];
                                float aa = s_aarea[lane];
                                float xx1 = fmaxf(ab.x, wb.x), yy1 = fmaxf(ab.y, wb.y);
                                float xx2 = fminf(ab.z, wb.z), yy2 = fminf(ab.w, wb.w);
                                float iw = fmaxf(xx2 - xx1, 0.f), ih = fmaxf(yy2 - yy1, 0.f);
                                float inter = iw * ih;
                                float den = (aa + war) - inter;
                                sup = iou_gt_half(inter, den);
                            }
                            if (__ballot(sup) == 0ull) {
                                if (lane == 0) {
                                    orow[na * 5 + 0] = wscore;
                                    orow[na * 5 + 1] = wb.x; orow[na * 5 + 2] = wb.y;
                                    orow[na * 5 + 3] = wb.z; orow[na * 5 + 4] = wb.w;
                                    s_abox[na] = wb;
                                    s_aarea[na] = war;
                                }
                                na++;
                            }
                        }
                        if (lane == 0) s_ctrl[0] = na;
                    }
                    __syncthreads();
                }
                if (s_ctrl[0] >= TOPK) break;
            }
            // --- tranche done ---
            if (s_ctrl[0] >= TOPK || trHi >= NBK) break;
            if (t == 0) s_ctrl[12] = trHi;
            __syncthreads();
        }
    } else {
        // ===== exact windowed path (single bucket > TRC; P~0): strided conf scan =====
        float hi = 1.0f, delta = 0.02f;
        while (true) {
            if (s_ctrl[0] >= TOPK || hi <= 0.5f) break;
            float lo = fmaxf(hi - delta, 0.5f);
            if (t == 0) s_ctrl[1] = 0;
            __syncthreads();
            for (int a = t; a < NA; a += 256) {
                float v = cp[(size_t)a * NC];
                if (v > lo && v <= hi) {
                    int p = atomicAdd(&s_ctrl[1], 1);
                    if (p < TRC) s_ix[p] = (unsigned short)a;
                }
            }
            __syncthreads();
            int m = s_ctrl[1];
            if (m > TRC) { delta *= 0.5f; continue; }
            if (wv == 0) {
                int na = s_ctrl[0];
                while (na < TOPK) {
                    unsigned long long bk = 0ull; int bpos = 0;
                    for (int i = lane; i < m; i += 64) {
                        int av = (int)s_ix[i];
                        if (av != 0xFFFF) {
                            float v = cp[(size_t)av * NC];
                            unsigned long long k =
                                ((unsigned long long)__float_as_uint(v) << 32) |
                                (unsigned)(16383 - av);
                            if (k > bk) { bk = k; bpos = i; }
                        }
                    }
                    for (int off = 32; off; off >>= 1) {
                        unsigned long long ok = __shfl_xor(bk, off);
                        int op = __shfl_xor(bpos, off);
                        if (ok > bk) { bk = ok; bpos = op; }
                    }
                    if (bk == 0ull) break;
                    int a = (int)s_ix[bpos];
                    float wscore = __uint_as_float((unsigned)(bk >> 32));
                    if (lane == 0) s_ix[bpos] = 0xFFFFu;
                    float4 wb = bb[a];
                    float war = (wb.z - wb.x) * (wb.w - wb.y);
                    bool sup = false;
                    if (lane < na) {
                        float4 ab = s_abox[lane];
                        float aa = s_aarea[lane];
                        float xx1 = fmaxf(ab.x, wb.x), yy1 = fmaxf(ab.y, wb.y);
                        float xx2 = fminf(ab.z, wb.z), yy2 = fminf(ab.w, wb.w);
                        float iw = fmaxf(xx2 - xx1, 0.f), ih = fmaxf(yy2 - yy1, 0.f);
                        float inter = iw * ih;
                        float den = (aa + war) - inter;
                        sup = iou_gt_half(inter, den);
                    }
                    if (__ballot(sup) == 0ull) {
                        if (lane == 0) {
                            orow[na * 5 + 0] = wscore;
                            orow[na * 5 + 1] = wb.x; orow[na * 5 + 2] = wb.y;
                            orow[na * 5 + 3] = wb.z; orow[na * 5 + 4] = wb.w;
                            s_abox[na] = wb;
                            s_aarea[na] = war;
                        }
                        na++;
                    }
                }
                if (lane == 0) s_ctrl[0] = na;
            }
            __syncthreads();
            hi = lo;
        }
    }

    __syncthreads();
    const int naF = s_ctrl[0];
    for (int z = naF * 5 + t; z < TOPK * 5; z += 256) orow[z] = 0.f;
}

// ============== round-1 fallback (only if ws too small for fast path) ==============
#define OTHREADS 1024
#define OCAP 10240
#define OJMAX 10

__global__ __launch_bounds__(OTHREADS) void nms_old_k(const float* __restrict__ conf,
                                                      const float* __restrict__ boxes,
                                                      float* __restrict__ out) {
#pragma clang fp contract(off)
    const int blk = blockIdx.x;
    const int b = blk / NC, c = blk - b * NC;
    const int t = threadIdx.x;
    const int lane = t & 63, wid = t >> 6;
    __shared__ float s_val[OCAP];
    __shared__ unsigned short s_idx[OCAP];
    __shared__ float s_ps[2][16];
    __shared__ int s_pa[2][16];
    __shared__ int s_n;
    if (t == 0) s_n = 0;
    __syncthreads();
    const float* cp = conf + ((size_t)b * NA) * NC + c;
    float v[NA / OTHREADS];
#pragma unroll
    for (int r = 0; r < NA / OTHREADS; ++r)
        v[r] = cp[(size_t)(r * OTHREADS + t) * NC];
#pragma unroll
    for (int r = 0; r < NA / OTHREADS; ++r) {
        int a = r * OTHREADS + t;
        bool alive = v[r] > 0.5f;
        unsigned long long m = __ballot(alive);
        int cnt = __popcll(m);
        int base = 0;
        if (lane == 0 && cnt) base = atomicAdd(&s_n, cnt);
        base = __shfl(base, 0);
        if (alive) {
            int p = base + __popcll(m & ((1ull << lane) - 1));
            if (p < OCAP) { s_val[p] = v[r]; s_idx[p] = (unsigned short)a; }
        }
    }
    __syncthreads();
    int n = s_n; if (n > OCAP) n = OCAP;
    const int jn = (n + OTHREADS - 1) / OTHREADS;
    const float4* bb = (const float4*)boxes + (size_t)b * NA;
    float sc[OJMAX]; float4 bx[OJMAX]; int ia[OJMAX];
#pragma unroll
    for (int j = 0; j < OJMAX; ++j) {
        sc[j] = NEGF; ia[j] = 0x7fffffff; bx[j] = make_float4(0.f, 0.f, 0.f, 0.f);
        int p = j * OTHREADS + t;
        if (p < n) { sc[j] = s_val[p]; ia[j] = (int)s_idx[p]; bx[j] = bb[ia[j]]; }
    }
    float* orow = out + (size_t)blk * (TOPK * 5);
    int k = 0;
    for (; k < TOPK; ++k) {
        float ms = NEGF; int ma = 0x7fffffff;
#pragma unroll
        for (int j = 0; j < OJMAX; ++j) {
            if (j < jn) {
                bool better = (sc[j] > ms) || (sc[j] == ms && ia[j] < ma);
                ms = better ? sc[j] : ms;
                ma = better ? ia[j] : ma;
            }
        }
#pragma unroll
        for (int off = 32; off; off >>= 1) {
            float os = __shfl_xor(ms, off);
            int oa = __shfl_xor(ma, off);
            if (os > ms || (os == ms && oa < ma)) { ms = os; ma = oa; }
        }
        int pb = k & 1;
        if (lane == 0) { s_ps[pb][wid] = ms; s_pa[pb][wid] = ma; }
        __syncthreads();
        float wsv = NEGF; int wa = 0x7fffffff;
#pragma unroll
        for (int w = 0; w < 16; ++w) {
            float os = s_ps[pb][w]; int oa = s_pa[pb][w];
            if (os > wsv || (os == wsv && oa < wa)) { wsv = os; wa = oa; }
        }
        if (!(wsv > NEGF)) break;
        float4 wb = bb[wa];
        float warea = (wb.z - wb.x) * (wb.w - wb.y);
        if (t == 0) {
            orow[k * 5 + 0] = wsv;
            orow[k * 5 + 1] = wb.x; orow[k * 5 + 2] = wb.y;
            orow[k * 5 + 3] = wb.z; orow[k * 5 + 4] = wb.w;
        }
#pragma unroll
        for (int j = 0; j < OJMAX; ++j) {
            if (j < jn) {
                float xx1 = fmaxf(wb.x, bx[j].x);
                float yy1 = fmaxf(wb.y, bx[j].y);
                float xx2 = fminf(wb.z, bx[j].z);
                float yy2 = fminf(wb.w, bx[j].w);
                float iw = fmaxf(xx2 - xx1, 0.f);
                float ih = fmaxf(yy2 - yy1, 0.f);
                float inter = iw * ih;
                float aj = (bx[j].z - bx[j].x) * (bx[j].w - bx[j].y);
                float denom = (warea + aj) - inter;
                bool supp = ((double)inter > (double)denom * SUPC) || (ia[j] == wa);
                if (supp) sc[j] = NEGF;
            }
        }
    }
    for (int z = k * 5 + t; z < TOPK * 5; z += OTHREADS) orow[z] = 0.f;
}

extern "C" void kernel_launch(void* const* d_in, const int* in_sizes, int n_in,
                              void* d_out, int out_size, void* d_ws, size_t ws_size,
                              hipStream_t stream) {
    const float* conf = (const float*)d_in[0];   // [B,A,C] f32
    const float* loc  = (const float*)d_in[1];   // [B,A,4] f32
    const float* anc  = (const float*)d_in[2];   // [A,4]   f32
    float* boxes = (float*)d_ws;

    if (ws_size >= WS_FULL) {
        unsigned char* confT = (unsigned char*)((char*)d_ws + WS_CONFT_OFF);
        dim3 tg(NA / TSLAB, NB, 2);              // z=0: transpose, z=1: decode
        prep_k<<<tg, 256, 0, stream>>>(conf, loc, anc, boxes, confT);
        nmsB6_k<<<NB * NC, 256, 0, stream>>>(confT, conf, boxes, (float*)d_out);
    } else {
        decode_k<<<(NB * NA + 255) / 256, 256, 0, stream>>>(loc, anc, boxes);
        nms_old_k<<<NB * NC, OTHREADS, 0, stream>>>(conf, boxes, (float*)d_out);
    }
}